// Round 4
// baseline (1106.192 us; speedup 1.0000x reference)
//
#include <hip/hip_runtime.h>
#include <math.h>

#define B_TOT 512
#define CQKV  256
#define CIN   128
#define HLEN  128

static constexpr float F_QR = 0.3f, F_KR = 0.3f, F_SV = 0.5f, F_SVE = 0.3f;
static constexpr float EPS = 1e-5f;

__device__ __forceinline__ unsigned short f2bf(float f) {
    unsigned u = __float_as_uint(f);
    unsigned r = u + 0x7fffu + ((u >> 16) & 1u);
    return (unsigned short)(r >> 16);
}
__device__ __forceinline__ float bfl(unsigned u) { return __uint_as_float(u << 16); }
__device__ __forceinline__ float bfh(unsigned u) { return __uint_as_float(u & 0xffff0000u); }

// ---------------------------------------------------------------------------
// Kernel 1: qkv[b][o][h] = sum_c w[o][c] * x[n][c][w][h],  b = n*64 + w
// 1024 blocks: each handles 128 of the 256 output channels (2x TLP).
// 8 independent accumulator chains per thread.
// ---------------------------------------------------------------------------
__global__ __launch_bounds__(256) void k_qkv(const float* __restrict__ x,
                                             const float* __restrict__ w,
                                             float* __restrict__ qkv) {
    int bid = blockIdx.x;
    int b = bid >> 1, og2 = bid & 1;
    int n = b >> 6, wi = b & 63;
    int t = threadIdx.x;
    int h = t & 127;
    int og = t >> 7;                          // 0/1 within this block's half
    int rowbase = og2 * 128 + og * 64;        // 64 rows per thread-group
    const float* xb = x + ((size_t)n * CIN * 64 + (size_t)wi) * HLEN;
    float xcol[CIN];
#pragma unroll
    for (int c = 0; c < CIN; ++c) xcol[c] = xb[(size_t)c * 64 * HLEN + h];

    float* out = qkv + ((size_t)b * CQKV + rowbase) * HLEN + h;
    const float* wbase = w + (size_t)rowbase * CIN;
    for (int r8 = 0; r8 < 64; r8 += 8) {
        float acc[8] = {0, 0, 0, 0, 0, 0, 0, 0};
#pragma unroll
        for (int c4 = 0; c4 < 32; ++c4) {
#pragma unroll
            for (int rr = 0; rr < 8; ++rr) {
                const float4 wv = *(const float4*)(wbase + (size_t)(r8 + rr) * CIN + c4 * 4);
                acc[rr] = fmaf(wv.x, xcol[4 * c4 + 0], acc[rr]);
                acc[rr] = fmaf(wv.y, xcol[4 * c4 + 1], acc[rr]);
                acc[rr] = fmaf(wv.z, xcol[4 * c4 + 2], acc[rr]);
                acc[rr] = fmaf(wv.w, xcol[4 * c4 + 3], acc[rr]);
            }
        }
#pragma unroll
        for (int rr = 0; rr < 8; ++rr) out[(size_t)(r8 + rr) * HLEN] = acc[rr];
    }
}

// ---------------------------------------------------------------------------
// Kernel 2: per-channel stats -> fused affine (scale, shift)
// ---------------------------------------------------------------------------
template <int MODE>
__global__ __launch_bounds__(256) void k_chstats(const float* __restrict__ data,
                                                 const float* __restrict__ ga,
                                                 const float* __restrict__ ba,
                                                 const float* __restrict__ gb,
                                                 const float* __restrict__ bb,
                                                 float* __restrict__ scale,
                                                 float* __restrict__ shift) {
    int o = blockIdx.x;
    int t = threadIdx.x;
    double s = 0.0, ss = 0.0;
    for (int idx = t; idx < B_TOT * HLEN; idx += 256) {
        int b = idx >> 7, h = idx & 127;
        float v = data[((size_t)b * CQKV + o) * HLEN + h];
        s += v;
        ss += (double)v * v;
    }
    __shared__ double sh_s[256], sh_ss[256];
    sh_s[t] = s; sh_ss[t] = ss;
    __syncthreads();
    for (int off = 128; off > 0; off >>= 1) {
        if (t < off) { sh_s[t] += sh_s[t + off]; sh_ss[t] += sh_ss[t + off]; }
        __syncthreads();
    }
    if (t == 0) {
        double cnt  = (double)B_TOT * HLEN;
        double mean = sh_s[0] / cnt;
        double var  = sh_ss[0] / cnt - mean * mean;
        float sc, sf;
        if (MODE == 0) {
            float r1 = rsqrtf((float)var + EPS);
            float v2 = ga[o] * ga[o] * (float)var * r1 * r1;
            sc = ga[o] * gb[o] * r1 * rsqrtf(v2 + EPS);
            sf = bb[o] - (float)mean * sc;
        } else {
            sc = ga[o] * rsqrtf((float)var + EPS);
            sf = ba[o] - (float)mean * sc;
        }
        scale[o] = sc;
        shift[o] = sf;
    }
}

// ---------------------------------------------------------------------------
// Tables for analytic score stats.
// ---------------------------------------------------------------------------
__global__ __launch_bounds__(128) void k_tables(const float* __restrict__ rel,
                                                float* __restrict__ Rq, float* __restrict__ Rk,
                                                float* __restrict__ TqT, float* __restrict__ TkT) {
    int bid = blockIdx.x;      // 0..127
    int i = threadIdx.x;       // 0..127
    int p = bid & 63;
    int c = p >> 3, c2 = p & 7;
    const float* ra = (bid < 64) ? (rel + c * 255)  : (rel + (8 + c) * 255);
    const float* rb = (bid < 64) ? (rel + c2 * 255) : (rel + (8 + c2) * 255);
    float tacc = 0.f;
    for (int kk = 0; kk < 128; ++kk) tacc = fmaf(ra[i + kk], rb[i + kk], tacc);
    if (bid < 64) TqT[i * 64 + p] = tacc; else TkT[i * 64 + p] = tacc;
    if (c2 == 0) {
        float racc = 0.f;
        for (int kk = 0; kk < 128; ++kk) racc += ra[i + kk];
        if (bid < 64) Rq[c * 128 + i] = racc; else Rk[c * 128 + i] = racc;
    }
}

// ---------------------------------------------------------------------------
// Analytic score stats per (b,g).
// ---------------------------------------------------------------------------
__global__ __launch_bounds__(64) void k_gram(const float* __restrict__ qkv,
                                             const float* __restrict__ scaleA,
                                             const float* __restrict__ shiftA,
                                             const float* __restrict__ Rq,
                                             const float* __restrict__ Rk,
                                             const float* __restrict__ TqT,
                                             const float* __restrict__ TkT,
                                             double* __restrict__ accS) {
    __shared__ float qs[8][132], ks[8][132];
    int blk = blockIdx.x, b = blk >> 3, g = blk & 7;
    int t = threadIdx.x;
    for (int idx = t; idx < 2048; idx += 64) {
        int cc = idx >> 7, h = idx & 127, o = g * 32 + cc;
        float v = qkv[((size_t)b * CQKV + o) * HLEN + h] * scaleA[o] + shiftA[o];
        if (cc < 8) qs[cc][h] = v; else ks[cc - 8][h] = v;
    }
    __syncthreads();
    int c = t >> 3, c2 = t & 7;
    float gq = 0, gk = 0, tq = 0, tk = 0;
    for (int i = 0; i < 128; ++i) {
        float a = qs[c][i] * qs[c2][i];
        float e = ks[c][i] * ks[c2][i];
        gq += a; gk += e;
        tq = fmaf(a, TqT[i * 64 + t], tq);
        tk = fmaf(e, TkT[i * 64 + t], tk);
    }
    float ssqk = gq * gk;
    float sqr = 0, skr = 0;
    float sq8[8], sk8[8];
#pragma unroll
    for (int c3 = 0; c3 < 8; ++c3) {
        float q0 = qs[c3][t], q1 = qs[c3][t + 64];
        float k0 = ks[c3][t], k1 = ks[c3][t + 64];
        sq8[c3] = q0 + q1; sk8[c3] = k0 + k1;
        sqr = fmaf(q0, Rq[c3 * 128 + t], sqr);
        sqr = fmaf(q1, Rq[c3 * 128 + t + 64], sqr);
        skr = fmaf(k0, Rk[c3 * 128 + t], skr);
        skr = fmaf(k1, Rk[c3 * 128 + t + 64], skr);
    }
#pragma unroll
    for (int off = 1; off < 64; off <<= 1) {
        ssqk += __shfl_xor(ssqk, off);
        tq   += __shfl_xor(tq, off);
        tk   += __shfl_xor(tk, off);
        sqr  += __shfl_xor(sqr, off);
        skr  += __shfl_xor(skr, off);
#pragma unroll
        for (int c3 = 0; c3 < 8; ++c3) {
            sq8[c3] += __shfl_xor(sq8[c3], off);
            sk8[c3] += __shfl_xor(sk8[c3], off);
        }
    }
    if (t == 0) {
        float sqk = 0;
#pragma unroll
        for (int c3 = 0; c3 < 8; ++c3) sqk += sq8[c3] * sk8[c3];
        atomicAdd(&accS[g * 2 + 0], (double)sqk);
        atomicAdd(&accS[g * 2 + 1], (double)ssqk);
        atomicAdd(&accS[(8 + g) * 2 + 0], (double)(F_QR * sqr));
        atomicAdd(&accS[(8 + g) * 2 + 1], (double)(F_QR * F_QR * tq));
        atomicAdd(&accS[(16 + g) * 2 + 0], (double)(F_KR * skr));
        atomicAdd(&accS[(16 + g) * 2 + 1], (double)(F_KR * F_KR * tk));
    }
}

__global__ void k_sfin(const double* __restrict__ accS,
                       const float* __restrict__ gs, const float* __restrict__ bs,
                       float* __restrict__ scaleS, float* __restrict__ shiftS) {
    int c = threadIdx.x;
    if (c < 24) {
        double cnt  = 512.0 * 128.0 * 128.0;
        double mean = accS[c * 2] / cnt;
        double var  = accS[c * 2 + 1] / cnt - mean * mean;
        float sc = gs[c] * rsqrtf((float)var + EPS);
        scaleS[c] = sc;
        shiftS[c] = bs[c] - (float)mean * sc;
    }
}

// ---------------------------------------------------------------------------
// Attention. Conflict-engineered LDS layouts:
//  - kT [128][12] f32 (48B rows): broadcast reads (2 distinct rows) -> free.
//  - vP [128][16] bf16 (32B rows): broadcast 2xb128 -> free.
//  - rel tables [255][12] bf16 (24B rows): 2x b64 per gather; bank group
//    3d mod 16 -> 16 groups -> 4-way (was 8-way with 16B rows).
//  - q read straight from global into registers (no LDS).
// ---------------------------------------------------------------------------
__global__ __launch_bounds__(256) void k_attn(const float* __restrict__ qkv,
                                              const float* __restrict__ scaleA,
                                              const float* __restrict__ shiftA,
                                              const float* __restrict__ rel,
                                              const float* __restrict__ scaleS,
                                              const float* __restrict__ shiftS,
                                              float* __restrict__ so) {
    __shared__ float kT[128][12];
    __shared__ unsigned short vP[128][16];
    __shared__ unsigned short rqT[255][12];
    __shared__ unsigned short rkT[255][12];
    __shared__ unsigned short rvA[255][12];
    __shared__ unsigned short rvB[255][12];
    int blk = blockIdx.x, b = blk >> 3, g = blk & 7;
    int t = threadIdx.x;
    int i = t >> 1, j0 = (t & 1) << 6;

    // q -> registers directly from global (overlaps with staging below)
    float qreg[8];
    {
        const float* qp = qkv + ((size_t)b * CQKV + g * 32) * HLEN + i;
#pragma unroll
        for (int c = 0; c < 8; ++c)
            qreg[c] = qp[(size_t)c * HLEN] * scaleA[g * 32 + c] + shiftA[g * 32 + c];
    }

    // stage k, v (24 channels x 128)
    for (int idx = t; idx < 24 * 128; idx += 256) {
        int cc = idx >> 7, h = idx & 127, o = g * 32 + 8 + cc;
        float v = qkv[((size_t)b * CQKV + o) * HLEN + h] * scaleA[o] + shiftA[o];
        if (cc < 8) kT[h][cc] = v;
        else        vP[h][cc - 8] = f2bf(v);
    }
    // stage rel tables as bf16, 12-ushort (24B) rows
    for (int idx = t; idx < 32 * 255; idx += 256) {
        int r = idx / 255, d = idx - r * 255;
        unsigned short us = f2bf(rel[r * 255 + d]);
        if (r < 8)       rqT[d][r] = us;
        else if (r < 16) rkT[d][r - 8] = us;
        else if (r < 24) rvA[d][r - 16] = us;
        else             rvB[d][r - 24] = us;
    }
    __syncthreads();

    float cA = scaleS[g], cB = F_QR * scaleS[8 + g], cC = F_KR * scaleS[16 + g];
    float shsum = shiftS[g] + shiftS[8 + g] + shiftS[16 + g];

    float p[64];
    float rowmax = -1e30f;
#pragma unroll
    for (int jj = 0; jj < 64; ++jj) {
        int j = j0 + jj;
        float4 ka = *(const float4*)&kT[j][0];
        float4 kb = *(const float4*)&kT[j][4];
        uint2 rqa = *(const uint2*)&rqT[i - j + 127][0];
        uint2 rqb = *(const uint2*)&rqT[i - j + 127][4];
        uint2 rka = *(const uint2*)&rkT[j - i + 127][0];
        uint2 rkb = *(const uint2*)&rkT[j - i + 127][4];
        float qk = fmaf(qreg[0], ka.x, fmaf(qreg[1], ka.y, fmaf(qreg[2], ka.z, fmaf(qreg[3], ka.w,
                   fmaf(qreg[4], kb.x, fmaf(qreg[5], kb.y, fmaf(qreg[6], kb.z, qreg[7] * kb.w)))))));
        float qr = fmaf(qreg[0], bfl(rqa.x), fmaf(qreg[1], bfh(rqa.x), fmaf(qreg[2], bfl(rqa.y), fmaf(qreg[3], bfh(rqa.y),
                   fmaf(qreg[4], bfl(rqb.x), fmaf(qreg[5], bfh(rqb.x), fmaf(qreg[6], bfl(rqb.y), qreg[7] * bfh(rqb.y))))))));
        float kr = fmaf(ka.x, bfl(rka.x), fmaf(ka.y, bfh(rka.x), fmaf(ka.z, bfl(rka.y), fmaf(ka.w, bfh(rka.y),
                   fmaf(kb.x, bfl(rkb.x), fmaf(kb.y, bfh(rkb.x), fmaf(kb.z, bfl(rkb.y), kb.w * bfh(rkb.y))))))));
        float s = fmaf(qk, cA, fmaf(qr, cB, fmaf(kr, cC, shsum)));
        p[jj] = s;
        rowmax = fmaxf(rowmax, s);
    }
    rowmax = fmaxf(rowmax, __shfl_xor(rowmax, 1));
    float rsum = 0.f;
#pragma unroll
    for (int jj = 0; jj < 64; ++jj) {
        float e = __expf(p[jj] - rowmax);
        p[jj] = e;
        rsum += e;
    }
    rsum += __shfl_xor(rsum, 1);
    float rn = 1.f / rsum;

    // ---- sv = P @ V^T (broadcast bf16 reads) ----
    float a0[16];
#pragma unroll
    for (int c = 0; c < 16; ++c) a0[c] = 0.f;
#pragma unroll
    for (int jj = 0; jj < 64; ++jj) {
        int j = j0 + jj;
        float pj = p[jj];
        uint4 va = *(const uint4*)&vP[j][0];
        uint4 vb = *(const uint4*)&vP[j][8];
        a0[0]  = fmaf(pj, bfl(va.x), a0[0]);  a0[1]  = fmaf(pj, bfh(va.x), a0[1]);
        a0[2]  = fmaf(pj, bfl(va.y), a0[2]);  a0[3]  = fmaf(pj, bfh(va.y), a0[3]);
        a0[4]  = fmaf(pj, bfl(va.z), a0[4]);  a0[5]  = fmaf(pj, bfh(va.z), a0[5]);
        a0[6]  = fmaf(pj, bfl(va.w), a0[6]);  a0[7]  = fmaf(pj, bfh(va.w), a0[7]);
        a0[8]  = fmaf(pj, bfl(vb.x), a0[8]);  a0[9]  = fmaf(pj, bfh(vb.x), a0[9]);
        a0[10] = fmaf(pj, bfl(vb.y), a0[10]); a0[11] = fmaf(pj, bfh(vb.y), a0[11]);
        a0[12] = fmaf(pj, bfl(vb.z), a0[12]); a0[13] = fmaf(pj, bfh(vb.z), a0[13]);
        a0[14] = fmaf(pj, bfl(vb.w), a0[14]); a0[15] = fmaf(pj, bfh(vb.w), a0[15]);
    }
#pragma unroll
    for (int c = 0; c < 16; ++c) a0[c] += __shfl_xor(a0[c], 1);
    {
        int cbase = (t & 1) * 8;
        float scv = F_SV * rn;
        float* sop = so + ((size_t)b * CQKV + g * 32) * HLEN + i;
#pragma unroll
        for (int c8 = 0; c8 < 8; ++c8) {
            int c = cbase + c8;
            sop[(size_t)(2 * c) * HLEN] = a0[c] * scv;
        }
    }

    // ---- sve = P (*) v_emb (Toeplitz, 4-way-max gathers) ----
    float a1[16];
#pragma unroll
    for (int c = 0; c < 16; ++c) a1[c] = 0.f;
#pragma unroll
    for (int jj = 0; jj < 64; ++jj) {
        int j = j0 + jj;
        int d = i - j + 127;
        float pj = p[jj];
        uint2 ra0 = *(const uint2*)&rvA[d][0];
        uint2 ra1 = *(const uint2*)&rvA[d][4];
        uint2 rb0 = *(const uint2*)&rvB[d][0];
        uint2 rb1 = *(const uint2*)&rvB[d][4];
        a1[0]  = fmaf(pj, bfl(ra0.x), a1[0]);  a1[1]  = fmaf(pj, bfh(ra0.x), a1[1]);
        a1[2]  = fmaf(pj, bfl(ra0.y), a1[2]);  a1[3]  = fmaf(pj, bfh(ra0.y), a1[3]);
        a1[4]  = fmaf(pj, bfl(ra1.x), a1[4]);  a1[5]  = fmaf(pj, bfh(ra1.x), a1[5]);
        a1[6]  = fmaf(pj, bfl(ra1.y), a1[6]);  a1[7]  = fmaf(pj, bfh(ra1.y), a1[7]);
        a1[8]  = fmaf(pj, bfl(rb0.x), a1[8]);  a1[9]  = fmaf(pj, bfh(rb0.x), a1[9]);
        a1[10] = fmaf(pj, bfl(rb0.y), a1[10]); a1[11] = fmaf(pj, bfh(rb0.y), a1[11]);
        a1[12] = fmaf(pj, bfl(rb1.x), a1[12]); a1[13] = fmaf(pj, bfh(rb1.x), a1[13]);
        a1[14] = fmaf(pj, bfl(rb1.y), a1[14]); a1[15] = fmaf(pj, bfh(rb1.y), a1[15]);
    }
#pragma unroll
    for (int c = 0; c < 16; ++c) a1[c] += __shfl_xor(a1[c], 1);
    {
        int cbase = (t & 1) * 8;
        float sce = F_SVE * rn;
        float* sop = so + ((size_t)b * CQKV + g * 32) * HLEN + i;
#pragma unroll
        for (int c8 = 0; c8 < 8; ++c8) {
            int c = cbase + c8;
            sop[(size_t)(2 * c + 1) * HLEN] = a1[c] * sce;
        }
    }
}

// ---------------------------------------------------------------------------
// Final affine + pair-sum + transpose
// ---------------------------------------------------------------------------
__global__ __launch_bounds__(256) void k_out(const float* __restrict__ so,
                                             const float* __restrict__ scale,
                                             const float* __restrict__ shift,
                                             float* __restrict__ out) {
    int b = blockIdx.x, n = b >> 6, wi = b & 63;
    int t = threadIdx.x, h = t & 127, half = t >> 7;
    for (int oc = half * 64; oc < half * 64 + 64; ++oc) {
        float v0 = so[((size_t)b * CQKV + 2 * oc) * HLEN + h] * scale[2 * oc] + shift[2 * oc];
        float v1 = so[((size_t)b * CQKV + 2 * oc + 1) * HLEN + h] * scale[2 * oc + 1] + shift[2 * oc + 1];
        out[(((size_t)n * 128 + oc) * 64 + wi) * HLEN + h] = v0 + v1;
    }
}

extern "C" void kernel_launch(void* const* d_in, const int* in_sizes, int n_in,
                              void* d_out, int out_size, void* d_ws, size_t ws_size,
                              hipStream_t stream) {
    const float* x   = (const float*)d_in[0];
    const float* w   = (const float*)d_in[1];
    const float* g1  = (const float*)d_in[2];
    const float* b1  = (const float*)d_in[3];
    const float* g2  = (const float*)d_in[4];
    const float* b2  = (const float*)d_in[5];
    const float* gs  = (const float*)d_in[6];
    const float* bs  = (const float*)d_in[7];
    const float* go  = (const float*)d_in[8];
    const float* bo  = (const float*)d_in[9];
    const float* rel = (const float*)d_in[10];
    float* out = (float*)d_out;

    float*  qkv    = (float*)d_ws;                      // 16,777,216 f
    float*  so     = qkv + (size_t)16777216;            // 16,777,216 f
    double* accS   = (double*)(so + (size_t)16777216);  // 48 d
    float*  scaleA = (float*)(accS + 48);
    float*  shiftA = scaleA + 256;
    float*  scaleS = shiftA + 256;                      // 24
    float*  shiftS = scaleS + 24;
    float*  scaleF = shiftS + 24;                       // 256
    float*  shiftF = scaleF + 256;
    float*  Rq     = shiftF + 256;                      // 1024
    float*  Rk     = Rq + 1024;                         // 1024
    float*  TqT    = Rk + 1024;                         // 8192
    float*  TkT    = TqT + 8192;                        // 8192

    hipMemsetAsync(accS, 0, 48 * sizeof(double), stream);

    k_qkv<<<1024, 256, 0, stream>>>(x, w, qkv);
    k_tables<<<128, 128, 0, stream>>>(rel, Rq, Rk, TqT, TkT);
    k_chstats<0><<<256, 256, 0, stream>>>(qkv, g1, b1, g2, b2, scaleA, shiftA);
    k_gram<<<4096, 64, 0, stream>>>(qkv, scaleA, shiftA, Rq, Rk, TqT, TkT, accS);
    k_sfin<<<1, 32, 0, stream>>>(accS, gs, bs, scaleS, shiftS);
    k_attn<<<4096, 256, 0, stream>>>(qkv, scaleA, shiftA, rel, scaleS, shiftS, so);
    k_chstats<1><<<256, 256, 0, stream>>>(so, go, bo, nullptr, nullptr, scaleF, shiftF);
    k_out<<<512, 256, 0, stream>>>(so, scaleF, shiftF, out);
}

// Round 5
// 1061.304 us; speedup vs baseline: 1.0423x; 1.0423x over previous
//
#include <hip/hip_runtime.h>
#include <math.h>

#define B_TOT 512
#define CQKV  256
#define CIN   128
#define HLEN  128

static constexpr float F_QR = 0.3f, F_KR = 0.3f, F_SV = 0.5f, F_SVE = 0.3f;
static constexpr float EPS = 1e-5f;

__device__ __forceinline__ unsigned short f2bf(float f) {
    unsigned u = __float_as_uint(f);
    unsigned r = u + 0x7fffu + ((u >> 16) & 1u);
    return (unsigned short)(r >> 16);
}
__device__ __forceinline__ float bfl(unsigned u) { return __uint_as_float(u << 16); }
__device__ __forceinline__ float bfh(unsigned u) { return __uint_as_float(u & 0xffff0000u); }

// ---------------------------------------------------------------------------
// Kernel 1: qkv[b][o][h] = sum_c w[o][c] * x[n][c][w][h],  b = n*64 + w
// 1024 blocks, 8 independent accumulator chains per thread.
// ---------------------------------------------------------------------------
__global__ __launch_bounds__(256) void k_qkv(const float* __restrict__ x,
                                             const float* __restrict__ w,
                                             float* __restrict__ qkv) {
    int bid = blockIdx.x;
    int b = bid >> 1, og2 = bid & 1;
    int n = b >> 6, wi = b & 63;
    int t = threadIdx.x;
    int h = t & 127;
    int og = t >> 7;
    int rowbase = og2 * 128 + og * 64;
    const float* xb = x + ((size_t)n * CIN * 64 + (size_t)wi) * HLEN;
    float xcol[CIN];
#pragma unroll
    for (int c = 0; c < CIN; ++c) xcol[c] = xb[(size_t)c * 64 * HLEN + h];

    float* out = qkv + ((size_t)b * CQKV + rowbase) * HLEN + h;
    const float* wbase = w + (size_t)rowbase * CIN;
    for (int r8 = 0; r8 < 64; r8 += 8) {
        float acc[8] = {0, 0, 0, 0, 0, 0, 0, 0};
#pragma unroll
        for (int c4 = 0; c4 < 32; ++c4) {
#pragma unroll
            for (int rr = 0; rr < 8; ++rr) {
                const float4 wv = *(const float4*)(wbase + (size_t)(r8 + rr) * CIN + c4 * 4);
                acc[rr] = fmaf(wv.x, xcol[4 * c4 + 0], acc[rr]);
                acc[rr] = fmaf(wv.y, xcol[4 * c4 + 1], acc[rr]);
                acc[rr] = fmaf(wv.z, xcol[4 * c4 + 2], acc[rr]);
                acc[rr] = fmaf(wv.w, xcol[4 * c4 + 3], acc[rr]);
            }
        }
#pragma unroll
        for (int rr = 0; rr < 8; ++rr) out[(size_t)(r8 + rr) * HLEN] = acc[rr];
    }
}

// ---------------------------------------------------------------------------
// Kernel 2: per-channel stats -> fused affine (scale, shift)
// ---------------------------------------------------------------------------
template <int MODE>
__global__ __launch_bounds__(256) void k_chstats(const float* __restrict__ data,
                                                 const float* __restrict__ ga,
                                                 const float* __restrict__ ba,
                                                 const float* __restrict__ gb,
                                                 const float* __restrict__ bb,
                                                 float* __restrict__ scale,
                                                 float* __restrict__ shift) {
    int o = blockIdx.x;
    int t = threadIdx.x;
    double s = 0.0, ss = 0.0;
    for (int idx = t; idx < B_TOT * HLEN; idx += 256) {
        int b = idx >> 7, h = idx & 127;
        float v = data[((size_t)b * CQKV + o) * HLEN + h];
        s += v;
        ss += (double)v * v;
    }
    __shared__ double sh_s[256], sh_ss[256];
    sh_s[t] = s; sh_ss[t] = ss;
    __syncthreads();
    for (int off = 128; off > 0; off >>= 1) {
        if (t < off) { sh_s[t] += sh_s[t + off]; sh_ss[t] += sh_ss[t + off]; }
        __syncthreads();
    }
    if (t == 0) {
        double cnt  = (double)B_TOT * HLEN;
        double mean = sh_s[0] / cnt;
        double var  = sh_ss[0] / cnt - mean * mean;
        float sc, sf;
        if (MODE == 0) {
            float r1 = rsqrtf((float)var + EPS);
            float v2 = ga[o] * ga[o] * (float)var * r1 * r1;
            sc = ga[o] * gb[o] * r1 * rsqrtf(v2 + EPS);
            sf = bb[o] - (float)mean * sc;
        } else {
            sc = ga[o] * rsqrtf((float)var + EPS);
            sf = ba[o] - (float)mean * sc;
        }
        scale[o] = sc;
        shift[o] = sf;
    }
}

// ---------------------------------------------------------------------------
// Tables for analytic score stats.
// ---------------------------------------------------------------------------
__global__ __launch_bounds__(128) void k_tables(const float* __restrict__ rel,
                                                float* __restrict__ Rq, float* __restrict__ Rk,
                                                float* __restrict__ TqT, float* __restrict__ TkT) {
    int bid = blockIdx.x;      // 0..127
    int i = threadIdx.x;       // 0..127
    int p = bid & 63;
    int c = p >> 3, c2 = p & 7;
    const float* ra = (bid < 64) ? (rel + c * 255)  : (rel + (8 + c) * 255);
    const float* rb = (bid < 64) ? (rel + c2 * 255) : (rel + (8 + c2) * 255);
    float tacc = 0.f;
    for (int kk = 0; kk < 128; ++kk) tacc = fmaf(ra[i + kk], rb[i + kk], tacc);
    if (bid < 64) TqT[i * 64 + p] = tacc; else TkT[i * 64 + p] = tacc;
    if (c2 == 0) {
        float racc = 0.f;
        for (int kk = 0; kk < 128; ++kk) racc += ra[i + kk];
        if (bid < 64) Rq[c * 128 + i] = racc; else Rk[c * 128 + i] = racc;
    }
}

// ---------------------------------------------------------------------------
// Analytic score stats per (b,g).
// ---------------------------------------------------------------------------
__global__ __launch_bounds__(64) void k_gram(const float* __restrict__ qkv,
                                             const float* __restrict__ scaleA,
                                             const float* __restrict__ shiftA,
                                             const float* __restrict__ Rq,
                                             const float* __restrict__ Rk,
                                             const float* __restrict__ TqT,
                                             const float* __restrict__ TkT,
                                             double* __restrict__ accS) {
    __shared__ float qs[8][132], ks[8][132];
    int blk = blockIdx.x, b = blk >> 3, g = blk & 7;
    int t = threadIdx.x;
    for (int idx = t; idx < 2048; idx += 64) {
        int cc = idx >> 7, h = idx & 127, o = g * 32 + cc;
        float v = qkv[((size_t)b * CQKV + o) * HLEN + h] * scaleA[o] + shiftA[o];
        if (cc < 8) qs[cc][h] = v; else ks[cc - 8][h] = v;
    }
    __syncthreads();
    int c = t >> 3, c2 = t & 7;
    float gq = 0, gk = 0, tq = 0, tk = 0;
    for (int i = 0; i < 128; ++i) {
        float a = qs[c][i] * qs[c2][i];
        float e = ks[c][i] * ks[c2][i];
        gq += a; gk += e;
        tq = fmaf(a, TqT[i * 64 + t], tq);
        tk = fmaf(e, TkT[i * 64 + t], tk);
    }
    float ssqk = gq * gk;
    float sqr = 0, skr = 0;
    float sq8[8], sk8[8];
#pragma unroll
    for (int c3 = 0; c3 < 8; ++c3) {
        float q0 = qs[c3][t], q1 = qs[c3][t + 64];
        float k0 = ks[c3][t], k1 = ks[c3][t + 64];
        sq8[c3] = q0 + q1; sk8[c3] = k0 + k1;
        sqr = fmaf(q0, Rq[c3 * 128 + t], sqr);
        sqr = fmaf(q1, Rq[c3 * 128 + t + 64], sqr);
        skr = fmaf(k0, Rk[c3 * 128 + t], skr);
        skr = fmaf(k1, Rk[c3 * 128 + t + 64], skr);
    }
#pragma unroll
    for (int off = 1; off < 64; off <<= 1) {
        ssqk += __shfl_xor(ssqk, off);
        tq   += __shfl_xor(tq, off);
        tk   += __shfl_xor(tk, off);
        sqr  += __shfl_xor(sqr, off);
        skr  += __shfl_xor(skr, off);
#pragma unroll
        for (int c3 = 0; c3 < 8; ++c3) {
            sq8[c3] += __shfl_xor(sq8[c3], off);
            sk8[c3] += __shfl_xor(sk8[c3], off);
        }
    }
    if (t == 0) {
        float sqk = 0;
#pragma unroll
        for (int c3 = 0; c3 < 8; ++c3) sqk += sq8[c3] * sk8[c3];
        atomicAdd(&accS[g * 2 + 0], (double)sqk);
        atomicAdd(&accS[g * 2 + 1], (double)ssqk);
        atomicAdd(&accS[(8 + g) * 2 + 0], (double)(F_QR * sqr));
        atomicAdd(&accS[(8 + g) * 2 + 1], (double)(F_QR * F_QR * tq));
        atomicAdd(&accS[(16 + g) * 2 + 0], (double)(F_KR * skr));
        atomicAdd(&accS[(16 + g) * 2 + 1], (double)(F_KR * F_KR * tk));
    }
}

__global__ void k_sfin(const double* __restrict__ accS,
                       const float* __restrict__ gs, const float* __restrict__ bs,
                       float* __restrict__ scaleS, float* __restrict__ shiftS) {
    int c = threadIdx.x;
    if (c < 24) {
        double cnt  = 512.0 * 128.0 * 128.0;
        double mean = accS[c * 2] / cnt;
        double var  = accS[c * 2 + 1] / cnt - mean * mean;
        float sc = gs[c] * rsqrtf((float)var + EPS);
        scaleS[c] = sc;
        shiftS[c] = bs[c] - (float)mean * sc;
    }
}

// ---------------------------------------------------------------------------
// Attention (round-3 structure + bank-uniform Toeplitz layout).
//  - rel tables packed 2-per-array, 40B rows (10 dwords): bank = 10d mod 32
//    covers all even residues per 16 consecutive d -> every b64 gather is
//    minimum-pass (uniform 4 requests/bank for 64 lanes), no excess conflict.
//  - kT [128][12] f32, vT [128][20] f32: broadcast reads (2 rows/wave), free.
//  - q via LDS qs (keeps VGPR at ~128 -> 4 waves/SIMD).
// ---------------------------------------------------------------------------
__global__ __launch_bounds__(256) void k_attn(const float* __restrict__ qkv,
                                              const float* __restrict__ scaleA,
                                              const float* __restrict__ shiftA,
                                              const float* __restrict__ rel,
                                              const float* __restrict__ scaleS,
                                              const float* __restrict__ shiftS,
                                              float* __restrict__ so) {
    __shared__ float qs[8][128];
    __shared__ float kT[128][12];
    __shared__ float vT[128][20];
    __shared__ __align__(16) unsigned short relA[255][20];  // rq ch0-7 | rk ch0-7 | pad
    __shared__ __align__(16) unsigned short relB[255][20];  // rvA ch0-7 | rvB ch0-7 | pad
    int blk = blockIdx.x, b = blk >> 3, g = blk & 7;
    int t = threadIdx.x;
    for (int idx = t; idx < 32 * 128; idx += 256) {
        int cc = idx >> 7, h = idx & 127, o = g * 32 + cc;
        float v = qkv[((size_t)b * CQKV + o) * HLEN + h] * scaleA[o] + shiftA[o];
        if (cc < 8)       qs[cc][h] = v;
        else if (cc < 16) kT[h][cc - 8] = v;
        else              vT[h][cc - 16] = v;
    }
    for (int idx = t; idx < 32 * 255; idx += 256) {
        int r = idx / 255, d = idx - r * 255;
        unsigned short us = f2bf(rel[r * 255 + d]);
        if (r < 16) relA[d][r] = us;
        else        relB[d][r - 16] = us;
    }
    __syncthreads();

    float cA = scaleS[g], cB = F_QR * scaleS[8 + g], cC = F_KR * scaleS[16 + g];
    float shsum = shiftS[g] + shiftS[8 + g] + shiftS[16 + g];

    int i = t >> 1, j0 = (t & 1) << 6;
    float qreg[8];
#pragma unroll
    for (int c = 0; c < 8; ++c) qreg[c] = qs[c][i];

    float p[64];
    float rowmax = -1e30f;
#pragma unroll
    for (int jj = 0; jj < 64; ++jj) {
        int j = j0 + jj;
        int dq = i - j + 127;
        int dk = j - i + 127;
        float4 ka = *(const float4*)&kT[j][0];
        float4 kb = *(const float4*)&kT[j][4];
        uint2 rqa = *(const uint2*)&relA[dq][0];
        uint2 rqb = *(const uint2*)&relA[dq][4];
        uint2 rka = *(const uint2*)&relA[dk][8];
        uint2 rkb = *(const uint2*)&relA[dk][12];
        float qk = fmaf(qreg[0], ka.x, fmaf(qreg[1], ka.y, fmaf(qreg[2], ka.z, fmaf(qreg[3], ka.w,
                   fmaf(qreg[4], kb.x, fmaf(qreg[5], kb.y, fmaf(qreg[6], kb.z, qreg[7] * kb.w)))))));
        float qr = fmaf(qreg[0], bfl(rqa.x), fmaf(qreg[1], bfh(rqa.x), fmaf(qreg[2], bfl(rqa.y), fmaf(qreg[3], bfh(rqa.y),
                   fmaf(qreg[4], bfl(rqb.x), fmaf(qreg[5], bfh(rqb.x), fmaf(qreg[6], bfl(rqb.y), qreg[7] * bfh(rqb.y))))))));
        float kr = fmaf(ka.x, bfl(rka.x), fmaf(ka.y, bfh(rka.x), fmaf(ka.z, bfl(rka.y), fmaf(ka.w, bfh(rka.y),
                   fmaf(kb.x, bfl(rkb.x), fmaf(kb.y, bfh(rkb.x), fmaf(kb.z, bfl(rkb.y), kb.w * bfh(rkb.y))))))));
        float s = fmaf(qk, cA, fmaf(qr, cB, fmaf(kr, cC, shsum)));
        p[jj] = s;
        rowmax = fmaxf(rowmax, s);
    }
    rowmax = fmaxf(rowmax, __shfl_xor(rowmax, 1));
    float rsum = 0.f;
#pragma unroll
    for (int jj = 0; jj < 64; ++jj) {
        float e = __expf(p[jj] - rowmax);
        p[jj] = e;
        rsum += e;
    }
    rsum += __shfl_xor(rsum, 1);
    float rn = 1.f / rsum;

    // ---- sv = P @ V^T (broadcast f32 reads) ----
    float a0[16];
#pragma unroll
    for (int c = 0; c < 16; ++c) a0[c] = 0.f;
#pragma unroll
    for (int jj = 0; jj < 64; ++jj) {
        int j = j0 + jj;
        float pj = p[jj];
        float4 v0 = *(const float4*)&vT[j][0];
        float4 v1 = *(const float4*)&vT[j][4];
        float4 v2 = *(const float4*)&vT[j][8];
        float4 v3 = *(const float4*)&vT[j][12];
        a0[0]  = fmaf(pj, v0.x, a0[0]);  a0[1]  = fmaf(pj, v0.y, a0[1]);
        a0[2]  = fmaf(pj, v0.z, a0[2]);  a0[3]  = fmaf(pj, v0.w, a0[3]);
        a0[4]  = fmaf(pj, v1.x, a0[4]);  a0[5]  = fmaf(pj, v1.y, a0[5]);
        a0[6]  = fmaf(pj, v1.z, a0[6]);  a0[7]  = fmaf(pj, v1.w, a0[7]);
        a0[8]  = fmaf(pj, v2.x, a0[8]);  a0[9]  = fmaf(pj, v2.y, a0[9]);
        a0[10] = fmaf(pj, v2.z, a0[10]); a0[11] = fmaf(pj, v2.w, a0[11]);
        a0[12] = fmaf(pj, v3.x, a0[12]); a0[13] = fmaf(pj, v3.y, a0[13]);
        a0[14] = fmaf(pj, v3.z, a0[14]); a0[15] = fmaf(pj, v3.w, a0[15]);
    }
#pragma unroll
    for (int c = 0; c < 16; ++c) a0[c] += __shfl_xor(a0[c], 1);
    {
        int cbase = (t & 1) * 8;
        float scv = F_SV * rn;
        float* sop = so + ((size_t)b * CQKV + g * 32) * HLEN + i;
#pragma unroll
        for (int c8 = 0; c8 < 8; ++c8) {
            int c = cbase + c8;
            sop[(size_t)(2 * c) * HLEN] = a0[c] * scv;
        }
    }

    // ---- sve = P (*) v_emb (bank-uniform b64 gathers) ----
    float a1[16];
#pragma unroll
    for (int c = 0; c < 16; ++c) a1[c] = 0.f;
#pragma unroll
    for (int jj = 0; jj < 64; ++jj) {
        int j = j0 + jj;
        int d = i - j + 127;
        float pj = p[jj];
        uint2 ra0 = *(const uint2*)&relB[d][0];
        uint2 ra1 = *(const uint2*)&relB[d][4];
        uint2 rb0 = *(const uint2*)&relB[d][8];
        uint2 rb1 = *(const uint2*)&relB[d][12];
        a1[0]  = fmaf(pj, bfl(ra0.x), a1[0]);  a1[1]  = fmaf(pj, bfh(ra0.x), a1[1]);
        a1[2]  = fmaf(pj, bfl(ra0.y), a1[2]);  a1[3]  = fmaf(pj, bfh(ra0.y), a1[3]);
        a1[4]  = fmaf(pj, bfl(ra1.x), a1[4]);  a1[5]  = fmaf(pj, bfh(ra1.x), a1[5]);
        a1[6]  = fmaf(pj, bfl(ra1.y), a1[6]);  a1[7]  = fmaf(pj, bfh(ra1.y), a1[7]);
        a1[8]  = fmaf(pj, bfl(rb0.x), a1[8]);  a1[9]  = fmaf(pj, bfh(rb0.x), a1[9]);
        a1[10] = fmaf(pj, bfl(rb0.y), a1[10]); a1[11] = fmaf(pj, bfh(rb0.y), a1[11]);
        a1[12] = fmaf(pj, bfl(rb1.x), a1[12]); a1[13] = fmaf(pj, bfh(rb1.x), a1[13]);
        a1[14] = fmaf(pj, bfl(rb1.y), a1[14]); a1[15] = fmaf(pj, bfh(rb1.y), a1[15]);
    }
#pragma unroll
    for (int c = 0; c < 16; ++c) a1[c] += __shfl_xor(a1[c], 1);
    {
        int cbase = (t & 1) * 8;
        float sce = F_SVE * rn;
        float* sop = so + ((size_t)b * CQKV + g * 32) * HLEN + i;
#pragma unroll
        for (int c8 = 0; c8 < 8; ++c8) {
            int c = cbase + c8;
            sop[(size_t)(2 * c + 1) * HLEN] = a1[c] * sce;
        }
    }
}

// ---------------------------------------------------------------------------
// Final affine + pair-sum + transpose
// ---------------------------------------------------------------------------
__global__ __launch_bounds__(256) void k_out(const float* __restrict__ so,
                                             const float* __restrict__ scale,
                                             const float* __restrict__ shift,
                                             float* __restrict__ out) {
    int b = blockIdx.x, n = b >> 6, wi = b & 63;
    int t = threadIdx.x, h = t & 127, half = t >> 7;
    for (int oc = half * 64; oc < half * 64 + 64; ++oc) {
        float v0 = so[((size_t)b * CQKV + 2 * oc) * HLEN + h] * scale[2 * oc] + shift[2 * oc];
        float v1 = so[((size_t)b * CQKV + 2 * oc + 1) * HLEN + h] * scale[2 * oc + 1] + shift[2 * oc + 1];
        out[(((size_t)n * 128 + oc) * 64 + wi) * HLEN + h] = v0 + v1;
    }
}

extern "C" void kernel_launch(void* const* d_in, const int* in_sizes, int n_in,
                              void* d_out, int out_size, void* d_ws, size_t ws_size,
                              hipStream_t stream) {
    const float* x   = (const float*)d_in[0];
    const float* w   = (const float*)d_in[1];
    const float* g1  = (const float*)d_in[2];
    const float* b1  = (const float*)d_in[3];
    const float* g2  = (const float*)d_in[4];
    const float* b2  = (const float*)d_in[5];
    const float* gs  = (const float*)d_in[6];
    const float* bs  = (const float*)d_in[7];
    const float* go  = (const float*)d_in[8];
    const float* bo  = (const float*)d_in[9];
    const float* rel = (const float*)d_in[10];
    float* out = (float*)d_out;

    float*  qkv    = (float*)d_ws;                      // 16,777,216 f
    float*  so     = qkv + (size_t)16777216;            // 16,777,216 f
    double* accS   = (double*)(so + (size_t)16777216);  // 48 d
    float*  scaleA = (float*)(accS + 48);
    float*  shiftA = scaleA + 256;
    float*  scaleS = shiftA + 256;                      // 24
    float*  shiftS = scaleS + 24;
    float*  scaleF = shiftS + 24;                       // 256
    float*  shiftF = scaleF + 256;
    float*  Rq     = shiftF + 256;                      // 1024
    float*  Rk     = Rq + 1024;                         // 1024
    float*  TqT    = Rk + 1024;                         // 8192
    float*  TkT    = TqT + 8192;                        // 8192

    hipMemsetAsync(accS, 0, 48 * sizeof(double), stream);

    k_qkv<<<1024, 256, 0, stream>>>(x, w, qkv);
    k_tables<<<128, 128, 0, stream>>>(rel, Rq, Rk, TqT, TkT);
    k_chstats<0><<<256, 256, 0, stream>>>(qkv, g1, b1, g2, b2, scaleA, shiftA);
    k_gram<<<4096, 64, 0, stream>>>(qkv, scaleA, shiftA, Rq, Rk, TqT, TkT, accS);
    k_sfin<<<1, 32, 0, stream>>>(accS, gs, bs, scaleS, shiftS);
    k_attn<<<4096, 256, 0, stream>>>(qkv, scaleA, shiftA, rel, scaleS, shiftS, so);
    k_chstats<1><<<256, 256, 0, stream>>>(so, go, bo, nullptr, nullptr, scaleF, shiftF);
    k_out<<<512, 256, 0, stream>>>(so, scaleF, shiftF, out);
}

// Round 6
// 815.655 us; speedup vs baseline: 1.3562x; 1.3012x over previous
//
#include <hip/hip_runtime.h>
#include <math.h>

#define B_TOT 512
#define CQKV  256
#define CIN   128
#define HLEN  128

static constexpr float F_QR = 0.3f, F_KR = 0.3f, F_SV = 0.5f, F_SVE = 0.3f;
static constexpr float EPS = 1e-5f;

typedef __attribute__((ext_vector_type(8))) short short8v;
typedef __attribute__((ext_vector_type(4))) float float4v;

__device__ __forceinline__ unsigned short f2bf(float f) {
    unsigned u = __float_as_uint(f);
    unsigned r = u + 0x7fffu + ((u >> 16) & 1u);
    return (unsigned short)(r >> 16);
}
__device__ __forceinline__ float bfl(unsigned u) { return __uint_as_float(u << 16); }
__device__ __forceinline__ float bfh(unsigned u) { return __uint_as_float(u & 0xffff0000u); }

// ---------------------------------------------------------------------------
// Kernel 1: qkv[b][o][h] = sum_c w[o][c] * x[n][c][w][h],  b = n*64 + w
// ---------------------------------------------------------------------------
__global__ __launch_bounds__(256) void k_qkv(const float* __restrict__ x,
                                             const float* __restrict__ w,
                                             float* __restrict__ qkv) {
    int bid = blockIdx.x;
    int b = bid >> 1, og2 = bid & 1;
    int n = b >> 6, wi = b & 63;
    int t = threadIdx.x;
    int h = t & 127;
    int og = t >> 7;
    int rowbase = og2 * 128 + og * 64;
    const float* xb = x + ((size_t)n * CIN * 64 + (size_t)wi) * HLEN;
    float xcol[CIN];
#pragma unroll
    for (int c = 0; c < CIN; ++c) xcol[c] = xb[(size_t)c * 64 * HLEN + h];

    float* out = qkv + ((size_t)b * CQKV + rowbase) * HLEN + h;
    const float* wbase = w + (size_t)rowbase * CIN;
    for (int r8 = 0; r8 < 64; r8 += 8) {
        float acc[8] = {0, 0, 0, 0, 0, 0, 0, 0};
#pragma unroll
        for (int c4 = 0; c4 < 32; ++c4) {
#pragma unroll
            for (int rr = 0; rr < 8; ++rr) {
                const float4 wv = *(const float4*)(wbase + (size_t)(r8 + rr) * CIN + c4 * 4);
                acc[rr] = fmaf(wv.x, xcol[4 * c4 + 0], acc[rr]);
                acc[rr] = fmaf(wv.y, xcol[4 * c4 + 1], acc[rr]);
                acc[rr] = fmaf(wv.z, xcol[4 * c4 + 2], acc[rr]);
                acc[rr] = fmaf(wv.w, xcol[4 * c4 + 3], acc[rr]);
            }
        }
#pragma unroll
        for (int rr = 0; rr < 8; ++rr) out[(size_t)(r8 + rr) * HLEN] = acc[rr];
    }
}

// ---------------------------------------------------------------------------
// Kernel 2: per-channel stats -> fused affine (scale, shift)
// ---------------------------------------------------------------------------
template <int MODE>
__global__ __launch_bounds__(256) void k_chstats(const float* __restrict__ data,
                                                 const float* __restrict__ ga,
                                                 const float* __restrict__ ba,
                                                 const float* __restrict__ gb,
                                                 const float* __restrict__ bb,
                                                 float* __restrict__ scale,
                                                 float* __restrict__ shift) {
    int o = blockIdx.x;
    int t = threadIdx.x;
    double s = 0.0, ss = 0.0;
    for (int idx = t; idx < B_TOT * HLEN; idx += 256) {
        int b = idx >> 7, h = idx & 127;
        float v = data[((size_t)b * CQKV + o) * HLEN + h];
        s += v;
        ss += (double)v * v;
    }
    __shared__ double sh_s[256], sh_ss[256];
    sh_s[t] = s; sh_ss[t] = ss;
    __syncthreads();
    for (int off = 128; off > 0; off >>= 1) {
        if (t < off) { sh_s[t] += sh_s[t + off]; sh_ss[t] += sh_ss[t + off]; }
        __syncthreads();
    }
    if (t == 0) {
        double cnt  = (double)B_TOT * HLEN;
        double mean = sh_s[0] / cnt;
        double var  = sh_ss[0] / cnt - mean * mean;
        float sc, sf;
        if (MODE == 0) {
            float r1 = rsqrtf((float)var + EPS);
            float v2 = ga[o] * ga[o] * (float)var * r1 * r1;
            sc = ga[o] * gb[o] * r1 * rsqrtf(v2 + EPS);
            sf = bb[o] - (float)mean * sc;
        } else {
            sc = ga[o] * rsqrtf((float)var + EPS);
            sf = ba[o] - (float)mean * sc;
        }
        scale[o] = sc;
        shift[o] = sf;
    }
}

// ---------------------------------------------------------------------------
// Tables for analytic score stats.
// ---------------------------------------------------------------------------
__global__ __launch_bounds__(128) void k_tables(const float* __restrict__ rel,
                                                float* __restrict__ Rq, float* __restrict__ Rk,
                                                float* __restrict__ TqT, float* __restrict__ TkT) {
    int bid = blockIdx.x;      // 0..127
    int i = threadIdx.x;       // 0..127
    int p = bid & 63;
    int c = p >> 3, c2 = p & 7;
    const float* ra = (bid < 64) ? (rel + c * 255)  : (rel + (8 + c) * 255);
    const float* rb = (bid < 64) ? (rel + c2 * 255) : (rel + (8 + c2) * 255);
    float tacc = 0.f;
    for (int kk = 0; kk < 128; ++kk) tacc = fmaf(ra[i + kk], rb[i + kk], tacc);
    if (bid < 64) TqT[i * 64 + p] = tacc; else TkT[i * 64 + p] = tacc;
    if (c2 == 0) {
        float racc = 0.f;
        for (int kk = 0; kk < 128; ++kk) racc += ra[i + kk];
        if (bid < 64) Rq[c * 128 + i] = racc; else Rk[c * 128 + i] = racc;
    }
}

// ---------------------------------------------------------------------------
// Analytic score stats per (b,g).
// ---------------------------------------------------------------------------
__global__ __launch_bounds__(64) void k_gram(const float* __restrict__ qkv,
                                             const float* __restrict__ scaleA,
                                             const float* __restrict__ shiftA,
                                             const float* __restrict__ Rq,
                                             const float* __restrict__ Rk,
                                             const float* __restrict__ TqT,
                                             const float* __restrict__ TkT,
                                             double* __restrict__ accS) {
    __shared__ float qs[8][132], ks[8][132];
    int blk = blockIdx.x, b = blk >> 3, g = blk & 7;
    int t = threadIdx.x;
    for (int idx = t; idx < 2048; idx += 64) {
        int cc = idx >> 7, h = idx & 127, o = g * 32 + cc;
        float v = qkv[((size_t)b * CQKV + o) * HLEN + h] * scaleA[o] + shiftA[o];
        if (cc < 8) qs[cc][h] = v; else ks[cc - 8][h] = v;
    }
    __syncthreads();
    int c = t >> 3, c2 = t & 7;
    float gq = 0, gk = 0, tq = 0, tk = 0;
    for (int i = 0; i < 128; ++i) {
        float a = qs[c][i] * qs[c2][i];
        float e = ks[c][i] * ks[c2][i];
        gq += a; gk += e;
        tq = fmaf(a, TqT[i * 64 + t], tq);
        tk = fmaf(e, TkT[i * 64 + t], tk);
    }
    float ssqk = gq * gk;
    float sqr = 0, skr = 0;
    float sq8[8], sk8[8];
#pragma unroll
    for (int c3 = 0; c3 < 8; ++c3) {
        float q0 = qs[c3][t], q1 = qs[c3][t + 64];
        float k0 = ks[c3][t], k1 = ks[c3][t + 64];
        sq8[c3] = q0 + q1; sk8[c3] = k0 + k1;
        sqr = fmaf(q0, Rq[c3 * 128 + t], sqr);
        sqr = fmaf(q1, Rq[c3 * 128 + t + 64], sqr);
        skr = fmaf(k0, Rk[c3 * 128 + t], skr);
        skr = fmaf(k1, Rk[c3 * 128 + t + 64], skr);
    }
#pragma unroll
    for (int off = 1; off < 64; off <<= 1) {
        ssqk += __shfl_xor(ssqk, off);
        tq   += __shfl_xor(tq, off);
        tk   += __shfl_xor(tk, off);
        sqr  += __shfl_xor(sqr, off);
        skr  += __shfl_xor(skr, off);
#pragma unroll
        for (int c3 = 0; c3 < 8; ++c3) {
            sq8[c3] += __shfl_xor(sq8[c3], off);
            sk8[c3] += __shfl_xor(sk8[c3], off);
        }
    }
    if (t == 0) {
        float sqk = 0;
#pragma unroll
        for (int c3 = 0; c3 < 8; ++c3) sqk += sq8[c3] * sk8[c3];
        atomicAdd(&accS[g * 2 + 0], (double)sqk);
        atomicAdd(&accS[g * 2 + 1], (double)ssqk);
        atomicAdd(&accS[(8 + g) * 2 + 0], (double)(F_QR * sqr));
        atomicAdd(&accS[(8 + g) * 2 + 1], (double)(F_QR * F_QR * tq));
        atomicAdd(&accS[(16 + g) * 2 + 0], (double)(F_KR * skr));
        atomicAdd(&accS[(16 + g) * 2 + 1], (double)(F_KR * F_KR * tk));
    }
}

__global__ void k_sfin(const double* __restrict__ accS,
                       const float* __restrict__ gs, const float* __restrict__ bs,
                       float* __restrict__ scaleS, float* __restrict__ shiftS) {
    int c = threadIdx.x;
    if (c < 24) {
        double cnt  = 512.0 * 128.0 * 128.0;
        double mean = accS[c * 2] / cnt;
        double var  = accS[c * 2 + 1] / cnt - mean * mean;
        float sc = gs[c] * rsqrtf((float)var + EPS);
        scaleS[c] = sc;
        shiftS[c] = bs[c] - (float)mean * sc;
    }
}

// ---------------------------------------------------------------------------
// Attention: round-3 structure (score loop / softmax / sve verbatim) with
// sv replaced by MFMA:  P (bf16, x rn) @ V^T (bf16 c-major), f32 accum.
//  - Pl [128][136] bf16: 272B rows (16B-aligned), frag reads min-pass.
//  - vB [16][136]  bf16: B-fragment = contiguous 8 j's of channel row.
//  - launch_bounds(256,4) pins VGPR <= 128 (round-4/5 regression guard).
// ---------------------------------------------------------------------------
__global__ __launch_bounds__(256, 4) void k_attn(const float* __restrict__ qkv,
                                                 const float* __restrict__ scaleA,
                                                 const float* __restrict__ shiftA,
                                                 const float* __restrict__ rel,
                                                 const float* __restrict__ scaleS,
                                                 const float* __restrict__ shiftS,
                                                 float* __restrict__ so) {
    __shared__ float qs[8][128];
    __shared__ float kT[128][12];
    __shared__ unsigned short vB[16][136];
    __shared__ unsigned short rqT[255][8];
    __shared__ unsigned short rkT[255][8];
    __shared__ unsigned short rvA[255][8];
    __shared__ unsigned short rvB[255][8];
    __shared__ unsigned short Pl[128][136];
    int blk = blockIdx.x, b = blk >> 3, g = blk & 7;
    int t = threadIdx.x;
    for (int idx = t; idx < 32 * 128; idx += 256) {
        int cc = idx >> 7, h = idx & 127, o = g * 32 + cc;
        float v = qkv[((size_t)b * CQKV + o) * HLEN + h] * scaleA[o] + shiftA[o];
        if (cc < 8)       qs[cc][h] = v;
        else if (cc < 16) kT[h][cc - 8] = v;
        else              vB[cc - 16][h] = f2bf(v);
    }
    for (int idx = t; idx < 32 * 255; idx += 256) {
        int r = idx / 255, d = idx - r * 255;
        unsigned short us = f2bf(rel[r * 255 + d]);
        if (r < 8)       rqT[d][r] = us;
        else if (r < 16) rkT[d][r - 8] = us;
        else if (r < 24) rvA[d][r - 16] = us;
        else             rvB[d][r - 24] = us;
    }
    __syncthreads();

    float cA = scaleS[g], cB = F_QR * scaleS[8 + g], cC = F_KR * scaleS[16 + g];
    float shsum = shiftS[g] + shiftS[8 + g] + shiftS[16 + g];

    int i = t >> 1, j0 = (t & 1) << 6;
    float qreg[8];
#pragma unroll
    for (int c = 0; c < 8; ++c) qreg[c] = qs[c][i];

    float p[64];
    float rowmax = -1e30f;
#pragma unroll
    for (int jj = 0; jj < 64; ++jj) {
        int j = j0 + jj;
        float4 ka = *(const float4*)&kT[j][0];
        float4 kb = *(const float4*)&kT[j][4];
        uint4 rq = *(const uint4*)&rqT[i - j + 127][0];
        uint4 rk = *(const uint4*)&rkT[j - i + 127][0];
        float qk = fmaf(qreg[0], ka.x, fmaf(qreg[1], ka.y, fmaf(qreg[2], ka.z, fmaf(qreg[3], ka.w,
                   fmaf(qreg[4], kb.x, fmaf(qreg[5], kb.y, fmaf(qreg[6], kb.z, qreg[7] * kb.w)))))));
        float qr = fmaf(qreg[0], bfl(rq.x), fmaf(qreg[1], bfh(rq.x), fmaf(qreg[2], bfl(rq.y), fmaf(qreg[3], bfh(rq.y),
                   fmaf(qreg[4], bfl(rq.z), fmaf(qreg[5], bfh(rq.z), fmaf(qreg[6], bfl(rq.w), qreg[7] * bfh(rq.w))))))));
        float kr = fmaf(ka.x, bfl(rk.x), fmaf(ka.y, bfh(rk.x), fmaf(ka.z, bfl(rk.y), fmaf(ka.w, bfh(rk.y),
                   fmaf(kb.x, bfl(rk.z), fmaf(kb.y, bfh(rk.z), fmaf(kb.z, bfl(rk.w), kb.w * bfh(rk.w))))))));
        float s = fmaf(qk, cA, fmaf(qr, cB, fmaf(kr, cC, shsum)));
        p[jj] = s;
        rowmax = fmaxf(rowmax, s);
    }
    rowmax = fmaxf(rowmax, __shfl_xor(rowmax, 1));
    float rsum = 0.f;
#pragma unroll
    for (int jj = 0; jj < 64; ++jj) {
        float e = __expf(p[jj] - rowmax);
        p[jj] = e;
        rsum += e;
    }
    rsum += __shfl_xor(rsum, 1);
    float rn = 1.f / rsum;

    // ---- write P*rn as bf16 to LDS (packed u32 pairs) ----
#pragma unroll
    for (int k = 0; k < 32; ++k) {
        unsigned lo = f2bf(p[2 * k] * rn);
        unsigned hi = f2bf(p[2 * k + 1] * rn);
        *(unsigned*)&Pl[i][j0 + 2 * k] = lo | (hi << 16);
    }

    // ---- sve = P (*) v_emb (register P, round-3 verbatim) ----
    float a1[16];
#pragma unroll
    for (int c = 0; c < 16; ++c) a1[c] = 0.f;
#pragma unroll
    for (int jj = 0; jj < 64; ++jj) {
        int j = j0 + jj;
        int d = i - j + 127;
        float pj = p[jj];
        uint4 ra = *(const uint4*)&rvA[d][0];
        uint4 rb = *(const uint4*)&rvB[d][0];
        a1[0]  = fmaf(pj, bfl(ra.x), a1[0]);  a1[1]  = fmaf(pj, bfh(ra.x), a1[1]);
        a1[2]  = fmaf(pj, bfl(ra.y), a1[2]);  a1[3]  = fmaf(pj, bfh(ra.y), a1[3]);
        a1[4]  = fmaf(pj, bfl(ra.z), a1[4]);  a1[5]  = fmaf(pj, bfh(ra.z), a1[5]);
        a1[6]  = fmaf(pj, bfl(ra.w), a1[6]);  a1[7]  = fmaf(pj, bfh(ra.w), a1[7]);
        a1[8]  = fmaf(pj, bfl(rb.x), a1[8]);  a1[9]  = fmaf(pj, bfh(rb.x), a1[9]);
        a1[10] = fmaf(pj, bfl(rb.y), a1[10]); a1[11] = fmaf(pj, bfh(rb.y), a1[11]);
        a1[12] = fmaf(pj, bfl(rb.z), a1[12]); a1[13] = fmaf(pj, bfh(rb.z), a1[13]);
        a1[14] = fmaf(pj, bfl(rb.w), a1[14]); a1[15] = fmaf(pj, bfh(rb.w), a1[15]);
    }
#pragma unroll
    for (int c = 0; c < 16; ++c) a1[c] += __shfl_xor(a1[c], 1);
    {
        int cbase = (t & 1) * 8;
        float sce = F_SVE * rn;
        float* sop = so + ((size_t)b * CQKV + g * 32) * HLEN + i;
#pragma unroll
        for (int c8 = 0; c8 < 8; ++c8) {
            int c = cbase + c8;
            sop[(size_t)(2 * c + 1) * HLEN] = a1[c] * sce;
        }
    }

    __syncthreads();

    // ---- sv via MFMA: D(16i x 16c) = P-tile(16 x 32j) x V(32j x 16c) ----
    {
        int w = t >> 6, l = t & 63;
        int lr = l & 15, lh = l >> 4;
#pragma unroll
        for (int it = 0; it < 2; ++it) {
            int itile = w * 2 + it;
            float4v acc = {0.f, 0.f, 0.f, 0.f};
#pragma unroll
            for (int ks = 0; ks < 4; ++ks) {
                short8v af = *(const short8v*)&Pl[itile * 16 + lr][ks * 32 + lh * 8];
                short8v bf = *(const short8v*)&vB[lr][ks * 32 + lh * 8];
                acc = __builtin_amdgcn_mfma_f32_16x16x32_bf16(af, bf, acc, 0, 0, 0);
            }
            int oc = g * 32 + 2 * lr;                       // even slot = sv
            float* sop = so + ((size_t)b * CQKV + oc) * HLEN + itile * 16 + lh * 4;
            float4 outv;
            outv.x = acc[0] * F_SV; outv.y = acc[1] * F_SV;
            outv.z = acc[2] * F_SV; outv.w = acc[3] * F_SV;
            *(float4*)sop = outv;
        }
    }
}

// ---------------------------------------------------------------------------
// Final affine + pair-sum + transpose
// ---------------------------------------------------------------------------
__global__ __launch_bounds__(256) void k_out(const float* __restrict__ so,
                                             const float* __restrict__ scale,
                                             const float* __restrict__ shift,
                                             float* __restrict__ out) {
    int b = blockIdx.x, n = b >> 6, wi = b & 63;
    int t = threadIdx.x, h = t & 127, half = t >> 7;
    for (int oc = half * 64; oc < half * 64 + 64; ++oc) {
        float v0 = so[((size_t)b * CQKV + 2 * oc) * HLEN + h] * scale[2 * oc] + shift[2 * oc];
        float v1 = so[((size_t)b * CQKV + 2 * oc + 1) * HLEN + h] * scale[2 * oc + 1] + shift[2 * oc + 1];
        out[(((size_t)n * 128 + oc) * 64 + wi) * HLEN + h] = v0 + v1;
    }
}

extern "C" void kernel_launch(void* const* d_in, const int* in_sizes, int n_in,
                              void* d_out, int out_size, void* d_ws, size_t ws_size,
                              hipStream_t stream) {
    const float* x   = (const float*)d_in[0];
    const float* w   = (const float*)d_in[1];
    const float* g1  = (const float*)d_in[2];
    const float* b1  = (const float*)d_in[3];
    const float* g2  = (const float*)d_in[4];
    const float* b2  = (const float*)d_in[5];
    const float* gs  = (const float*)d_in[6];
    const float* bs  = (const float*)d_in[7];
    const float* go  = (const float*)d_in[8];
    const float* bo  = (const float*)d_in[9];
    const float* rel = (const float*)d_in[10];
    float* out = (float*)d_out;

    float*  qkv    = (float*)d_ws;                      // 16,777,216 f
    float*  so     = qkv + (size_t)16777216;            // 16,777,216 f
    double* accS   = (double*)(so + (size_t)16777216);  // 48 d
    float*  scaleA = (float*)(accS + 48);
    float*  shiftA = scaleA + 256;
    float*  scaleS = shiftA + 256;                      // 24
    float*  shiftS = scaleS + 24;
    float*  scaleF = shiftS + 24;                       // 256
    float*  shiftF = scaleF + 256;
    float*  Rq     = shiftF + 256;                      // 1024
    float*  Rk     = Rq + 1024;                         // 1024
    float*  TqT    = Rk + 1024;                         // 8192
    float*  TkT    = TqT + 8192;                        // 8192

    hipMemsetAsync(accS, 0, 48 * sizeof(double), stream);

    k_qkv<<<1024, 256, 0, stream>>>(x, w, qkv);
    k_tables<<<128, 128, 0, stream>>>(rel, Rq, Rk, TqT, TkT);
    k_chstats<0><<<256, 256, 0, stream>>>(qkv, g1, b1, g2, b2, scaleA, shiftA);
    k_gram<<<4096, 64, 0, stream>>>(qkv, scaleA, shiftA, Rq, Rk, TqT, TkT, accS);
    k_sfin<<<1, 32, 0, stream>>>(accS, gs, bs, scaleS, shiftS);
    k_attn<<<4096, 256, 0, stream>>>(qkv, scaleA, shiftA, rel, scaleS, shiftS, so);
    k_chstats<1><<<256, 256, 0, stream>>>(so, go, bo, nullptr, nullptr, scaleF, shiftF);
    k_out<<<512, 256, 0, stream>>>(so, scaleF, shiftF, out);
}

// Round 7
// 554.467 us; speedup vs baseline: 1.9951x; 1.4711x over previous
//
#include <hip/hip_runtime.h>
#include <math.h>

#define B_TOT 512
#define CQKV  256
#define CIN   128
#define HLEN  128

static constexpr float F_QR = 0.3f, F_KR = 0.3f, F_SV = 0.5f, F_SVE = 0.3f;
static constexpr float EPS = 1e-5f;

typedef __attribute__((ext_vector_type(8))) short short8v;
typedef __attribute__((ext_vector_type(4))) float float4v;

__device__ __forceinline__ unsigned short f2bf(float f) {
    unsigned u = __float_as_uint(f);
    unsigned r = u + 0x7fffu + ((u >> 16) & 1u);
    return (unsigned short)(r >> 16);
}
__device__ __forceinline__ float bfl(unsigned u) { return __uint_as_float(u << 16); }
__device__ __forceinline__ float bfh(unsigned u) { return __uint_as_float(u & 0xffff0000u); }

// ---------------------------------------------------------------------------
// Kernel 1 (MFMA): qkv[b][o][h] = sum_c w[o][c] * x[n][c][w][h],  b = n*64+w.
// Viewed per n as GEMM: C[o][m] = W(256x128) @ Xn(128x8192), m = w*128+h.
// Block tile: 64o x 256m, K=128 in two 64-slices. X staged transposed
// [m][c] bf16 with 16B-block XOR swizzle (write conflicts are structural
// without it: lane m-stride => delta-dw ≡ 0 mod 32 for any aligned row).
// Fragment convention identical to round-6 verified sv-MFMA.
// ---------------------------------------------------------------------------
__global__ __launch_bounds__(256, 3) void k_qkv(const float* __restrict__ x,
                                                const float* __restrict__ w,
                                                float* __restrict__ qkv) {
    __shared__ unsigned short As[64][136];   // W tile bf16, row=o (272B rows)
    __shared__ unsigned short Xs[256][64];   // X slice bf16, row=m, col=swizzled c
    int bid = blockIdx.x;
    int n   = bid >> 7;
    int sub = bid & 127;
    int mt  = sub >> 2;            // 32 m-tiles of 256
    int ot  = sub & 3;             // 4 o-tiles of 64
    int m0  = mt << 8;
    int o0  = ot << 6;
    int t   = threadIdx.x;

    // stage W tile: 64 o x 128 c (bf16), conflict-benign contiguous writes
#pragma unroll
    for (int it = 0; it < 8; ++it) {
        int idx = it * 256 + t;
        int o = idx >> 5, c4 = (idx & 31) << 2;
        float4 wv = *(const float4*)(w + (size_t)(o0 + o) * CIN + c4);
        As[o][c4 + 0] = f2bf(wv.x);
        As[o][c4 + 1] = f2bf(wv.y);
        As[o][c4 + 2] = f2bf(wv.z);
        As[o][c4 + 3] = f2bf(wv.w);
    }

    const float* xn = x + (size_t)n * CIN * 8192 + m0;

    int wv_ = t >> 6, l = t & 63;
    int lr = l & 15, lh = l >> 4;
    int mw = wv_ << 6;             // wave's 64-m sub-range

    float4v acc[4][4];             // [o-subtile][m-subtile]
#pragma unroll
    for (int a = 0; a < 4; ++a)
#pragma unroll
        for (int b2 = 0; b2 < 4; ++b2) acc[a][b2] = (float4v){0.f, 0.f, 0.f, 0.f};

    for (int s = 0; s < 2; ++s) {
        int c0 = s << 6;
        __syncthreads();           // protect Xs from previous slice reads
        // stage X slice: 64 c-rows x 256 m, transposed into Xs[m][c^] bf16
#pragma unroll
        for (int it = 0; it < 16; ++it) {
            int c  = (it << 2) + (t >> 6);       // within-slice c (wave-uniform)
            int m4 = (t & 63) << 2;
            float4 xv = *(const float4*)(xn + (size_t)(c0 + c) * 8192 + m4);
            float vals[4] = {xv.x, xv.y, xv.z, xv.w};
#pragma unroll
            for (int j = 0; j < 4; ++j) {
                int m = m4 + j;
                int cs = (((c >> 3) ^ ((m >> 2) & 7)) << 3) | (c & 7);
                Xs[m][cs] = f2bf(vals[j]);
            }
        }
        __syncthreads();
        // 2 k-steps of 32
#pragma unroll
        for (int ks = 0; ks < 2; ++ks) {
            short8v af[4], bf[4];
#pragma unroll
            for (int a = 0; a < 4; ++a)
                af[a] = *(const short8v*)&As[a * 16 + lr][c0 + ks * 32 + lh * 8];
#pragma unroll
            for (int b2 = 0; b2 < 4; ++b2) {
                int m  = mw + b2 * 16 + lr;
                int cb = (ks * 4 + lh) ^ ((m >> 2) & 7);   // swizzled 8-block
                bf[b2] = *(const short8v*)&Xs[m][cb << 3];
            }
#pragma unroll
            for (int a = 0; a < 4; ++a)
#pragma unroll
                for (int b2 = 0; b2 < 4; ++b2)
                    acc[a][b2] = __builtin_amdgcn_mfma_f32_16x16x32_bf16(
                        af[a], bf[b2], acc[a][b2], 0, 0, 0);
        }
    }

    // write-out: o = o0 + a*16 + lh*4 + r,  m = m0 + mw + b2*16 + lr
#pragma unroll
    for (int a = 0; a < 4; ++a) {
#pragma unroll
        for (int b2 = 0; b2 < 4; ++b2) {
            int m  = m0 + mw + b2 * 16 + lr;
            int bb = n * 64 + (m >> 7);
            int h  = m & 127;
#pragma unroll
            for (int r = 0; r < 4; ++r) {
                int o = o0 + a * 16 + lh * 4 + r;
                qkv[((size_t)bb * CQKV + o) * HLEN + h] = acc[a][b2][r];
            }
        }
    }
}

// ---------------------------------------------------------------------------
// Kernel 2: per-channel stats -> fused affine (scale, shift)
// ---------------------------------------------------------------------------
template <int MODE>
__global__ __launch_bounds__(256) void k_chstats(const float* __restrict__ data,
                                                 const float* __restrict__ ga,
                                                 const float* __restrict__ ba,
                                                 const float* __restrict__ gb,
                                                 const float* __restrict__ bb,
                                                 float* __restrict__ scale,
                                                 float* __restrict__ shift) {
    int o = blockIdx.x;
    int t = threadIdx.x;
    double s = 0.0, ss = 0.0;
    for (int idx = t; idx < B_TOT * HLEN; idx += 256) {
        int b = idx >> 7, h = idx & 127;
        float v = data[((size_t)b * CQKV + o) * HLEN + h];
        s += v;
        ss += (double)v * v;
    }
    __shared__ double sh_s[256], sh_ss[256];
    sh_s[t] = s; sh_ss[t] = ss;
    __syncthreads();
    for (int off = 128; off > 0; off >>= 1) {
        if (t < off) { sh_s[t] += sh_s[t + off]; sh_ss[t] += sh_ss[t + off]; }
        __syncthreads();
    }
    if (t == 0) {
        double cnt  = (double)B_TOT * HLEN;
        double mean = sh_s[0] / cnt;
        double var  = sh_ss[0] / cnt - mean * mean;
        float sc, sf;
        if (MODE == 0) {
            float r1 = rsqrtf((float)var + EPS);
            float v2 = ga[o] * ga[o] * (float)var * r1 * r1;
            sc = ga[o] * gb[o] * r1 * rsqrtf(v2 + EPS);
            sf = bb[o] - (float)mean * sc;
        } else {
            sc = ga[o] * rsqrtf((float)var + EPS);
            sf = ba[o] - (float)mean * sc;
        }
        scale[o] = sc;
        shift[o] = sf;
    }
}

// ---------------------------------------------------------------------------
// Tables for analytic score stats.
// ---------------------------------------------------------------------------
__global__ __launch_bounds__(128) void k_tables(const float* __restrict__ rel,
                                                float* __restrict__ Rq, float* __restrict__ Rk,
                                                float* __restrict__ TqT, float* __restrict__ TkT) {
    int bid = blockIdx.x;      // 0..127
    int i = threadIdx.x;       // 0..127
    int p = bid & 63;
    int c = p >> 3, c2 = p & 7;
    const float* ra = (bid < 64) ? (rel + c * 255)  : (rel + (8 + c) * 255);
    const float* rb = (bid < 64) ? (rel + c2 * 255) : (rel + (8 + c2) * 255);
    float tacc = 0.f;
    for (int kk = 0; kk < 128; ++kk) tacc = fmaf(ra[i + kk], rb[i + kk], tacc);
    if (bid < 64) TqT[i * 64 + p] = tacc; else TkT[i * 64 + p] = tacc;
    if (c2 == 0) {
        float racc = 0.f;
        for (int kk = 0; kk < 128; ++kk) racc += ra[i + kk];
        if (bid < 64) Rq[c * 128 + i] = racc; else Rk[c * 128 + i] = racc;
    }
}

// ---------------------------------------------------------------------------
// Analytic score stats per (b,g).
// ---------------------------------------------------------------------------
__global__ __launch_bounds__(64) void k_gram(const float* __restrict__ qkv,
                                             const float* __restrict__ scaleA,
                                             const float* __restrict__ shiftA,
                                             const float* __restrict__ Rq,
                                             const float* __restrict__ Rk,
                                             const float* __restrict__ TqT,
                                             const float* __restrict__ TkT,
                                             double* __restrict__ accS) {
    __shared__ float qs[8][132], ks[8][132];
    int blk = blockIdx.x, b = blk >> 3, g = blk & 7;
    int t = threadIdx.x;
    for (int idx = t; idx < 2048; idx += 64) {
        int cc = idx >> 7, h = idx & 127, o = g * 32 + cc;
        float v = qkv[((size_t)b * CQKV + o) * HLEN + h] * scaleA[o] + shiftA[o];
        if (cc < 8) qs[cc][h] = v; else ks[cc - 8][h] = v;
    }
    __syncthreads();
    int c = t >> 3, c2 = t & 7;
    float gq = 0, gk = 0, tq = 0, tk = 0;
    for (int i = 0; i < 128; ++i) {
        float a = qs[c][i] * qs[c2][i];
        float e = ks[c][i] * ks[c2][i];
        gq += a; gk += e;
        tq = fmaf(a, TqT[i * 64 + t], tq);
        tk = fmaf(e, TkT[i * 64 + t], tk);
    }
    float ssqk = gq * gk;
    float sqr = 0, skr = 0;
    float sq8[8], sk8[8];
#pragma unroll
    for (int c3 = 0; c3 < 8; ++c3) {
        float q0 = qs[c3][t], q1 = qs[c3][t + 64];
        float k0 = ks[c3][t], k1 = ks[c3][t + 64];
        sq8[c3] = q0 + q1; sk8[c3] = k0 + k1;
        sqr = fmaf(q0, Rq[c3 * 128 + t], sqr);
        sqr = fmaf(q1, Rq[c3 * 128 + t + 64], sqr);
        skr = fmaf(k0, Rk[c3 * 128 + t], skr);
        skr = fmaf(k1, Rk[c3 * 128 + t + 64], skr);
    }
#pragma unroll
    for (int off = 1; off < 64; off <<= 1) {
        ssqk += __shfl_xor(ssqk, off);
        tq   += __shfl_xor(tq, off);
        tk   += __shfl_xor(tk, off);
        sqr  += __shfl_xor(sqr, off);
        skr  += __shfl_xor(skr, off);
#pragma unroll
        for (int c3 = 0; c3 < 8; ++c3) {
            sq8[c3] += __shfl_xor(sq8[c3], off);
            sk8[c3] += __shfl_xor(sk8[c3], off);
        }
    }
    if (t == 0) {
        float sqk = 0;
#pragma unroll
        for (int c3 = 0; c3 < 8; ++c3) sqk += sq8[c3] * sk8[c3];
        atomicAdd(&accS[g * 2 + 0], (double)sqk);
        atomicAdd(&accS[g * 2 + 1], (double)ssqk);
        atomicAdd(&accS[(8 + g) * 2 + 0], (double)(F_QR * sqr));
        atomicAdd(&accS[(8 + g) * 2 + 1], (double)(F_QR * F_QR * tq));
        atomicAdd(&accS[(16 + g) * 2 + 0], (double)(F_KR * skr));
        atomicAdd(&accS[(16 + g) * 2 + 1], (double)(F_KR * F_KR * tk));
    }
}

__global__ void k_sfin(const double* __restrict__ accS,
                       const float* __restrict__ gs, const float* __restrict__ bs,
                       float* __restrict__ scaleS, float* __restrict__ shiftS) {
    int c = threadIdx.x;
    if (c < 24) {
        double cnt  = 512.0 * 128.0 * 128.0;
        double mean = accS[c * 2] / cnt;
        double var  = accS[c * 2 + 1] / cnt - mean * mean;
        float sc = gs[c] * rsqrtf((float)var + EPS);
        scaleS[c] = sc;
        shiftS[c] = bs[c] - (float)mean * sc;
    }
}

// ---------------------------------------------------------------------------
// Attention: round-6 verbatim (score loop + softmax + sve on VALU,
// sv via MFMA with bf16 P in LDS).
// ---------------------------------------------------------------------------
__global__ __launch_bounds__(256, 4) void k_attn(const float* __restrict__ qkv,
                                                 const float* __restrict__ scaleA,
                                                 const float* __restrict__ shiftA,
                                                 const float* __restrict__ rel,
                                                 const float* __restrict__ scaleS,
                                                 const float* __restrict__ shiftS,
                                                 float* __restrict__ so) {
    __shared__ float qs[8][128];
    __shared__ float kT[128][12];
    __shared__ unsigned short vB[16][136];
    __shared__ unsigned short rqT[255][8];
    __shared__ unsigned short rkT[255][8];
    __shared__ unsigned short rvA[255][8];
    __shared__ unsigned short rvB[255][8];
    __shared__ unsigned short Pl[128][136];
    int blk = blockIdx.x, b = blk >> 3, g = blk & 7;
    int t = threadIdx.x;
    for (int idx = t; idx < 32 * 128; idx += 256) {
        int cc = idx >> 7, h = idx & 127, o = g * 32 + cc;
        float v = qkv[((size_t)b * CQKV + o) * HLEN + h] * scaleA[o] + shiftA[o];
        if (cc < 8)       qs[cc][h] = v;
        else if (cc < 16) kT[h][cc - 8] = v;
        else              vB[cc - 16][h] = f2bf(v);
    }
    for (int idx = t; idx < 32 * 255; idx += 256) {
        int r = idx / 255, d = idx - r * 255;
        unsigned short us = f2bf(rel[r * 255 + d]);
        if (r < 8)       rqT[d][r] = us;
        else if (r < 16) rkT[d][r - 8] = us;
        else if (r < 24) rvA[d][r - 16] = us;
        else             rvB[d][r - 24] = us;
    }
    __syncthreads();

    float cA = scaleS[g], cB = F_QR * scaleS[8 + g], cC = F_KR * scaleS[16 + g];
    float shsum = shiftS[g] + shiftS[8 + g] + shiftS[16 + g];

    int i = t >> 1, j0 = (t & 1) << 6;
    float qreg[8];
#pragma unroll
    for (int c = 0; c < 8; ++c) qreg[c] = qs[c][i];

    float p[64];
    float rowmax = -1e30f;
#pragma unroll
    for (int jj = 0; jj < 64; ++jj) {
        int j = j0 + jj;
        float4 ka = *(const float4*)&kT[j][0];
        float4 kb = *(const float4*)&kT[j][4];
        uint4 rq = *(const uint4*)&rqT[i - j + 127][0];
        uint4 rk = *(const uint4*)&rkT[j - i + 127][0];
        float qk = fmaf(qreg[0], ka.x, fmaf(qreg[1], ka.y, fmaf(qreg[2], ka.z, fmaf(qreg[3], ka.w,
                   fmaf(qreg[4], kb.x, fmaf(qreg[5], kb.y, fmaf(qreg[6], kb.z, qreg[7] * kb.w)))))));
        float qr = fmaf(qreg[0], bfl(rq.x), fmaf(qreg[1], bfh(rq.x), fmaf(qreg[2], bfl(rq.y), fmaf(qreg[3], bfh(rq.y),
                   fmaf(qreg[4], bfl(rq.z), fmaf(qreg[5], bfh(rq.z), fmaf(qreg[6], bfl(rq.w), qreg[7] * bfh(rq.w))))))));
        float kr = fmaf(ka.x, bfl(rk.x), fmaf(ka.y, bfh(rk.x), fmaf(ka.z, bfl(rk.y), fmaf(ka.w, bfh(rk.y),
                   fmaf(kb.x, bfl(rk.z), fmaf(kb.y, bfh(rk.z), fmaf(kb.z, bfl(rk.w), kb.w * bfh(rk.w))))))));
        float s = fmaf(qk, cA, fmaf(qr, cB, fmaf(kr, cC, shsum)));
        p[jj] = s;
        rowmax = fmaxf(rowmax, s);
    }
    rowmax = fmaxf(rowmax, __shfl_xor(rowmax, 1));
    float rsum = 0.f;
#pragma unroll
    for (int jj = 0; jj < 64; ++jj) {
        float e = __expf(p[jj] - rowmax);
        p[jj] = e;
        rsum += e;
    }
    rsum += __shfl_xor(rsum, 1);
    float rn = 1.f / rsum;

    // ---- write P*rn as bf16 to LDS (packed u32 pairs) ----
#pragma unroll
    for (int k = 0; k < 32; ++k) {
        unsigned lo = f2bf(p[2 * k] * rn);
        unsigned hi = f2bf(p[2 * k + 1] * rn);
        *(unsigned*)&Pl[i][j0 + 2 * k] = lo | (hi << 16);
    }

    // ---- sve = P (*) v_emb (register P) ----
    float a1[16];
#pragma unroll
    for (int c = 0; c < 16; ++c) a1[c] = 0.f;
#pragma unroll
    for (int jj = 0; jj < 64; ++jj) {
        int j = j0 + jj;
        int d = i - j + 127;
        float pj = p[jj];
        uint4 ra = *(const uint4*)&rvA[d][0];
        uint4 rb = *(const uint4*)&rvB[d][0];
        a1[0]  = fmaf(pj, bfl(ra.x), a1[0]);  a1[1]  = fmaf(pj, bfh(ra.x), a1[1]);
        a1[2]  = fmaf(pj, bfl(ra.y), a1[2]);  a1[3]  = fmaf(pj, bfh(ra.y), a1[3]);
        a1[4]  = fmaf(pj, bfl(ra.z), a1[4]);  a1[5]  = fmaf(pj, bfh(ra.z), a1[5]);
        a1[6]  = fmaf(pj, bfl(ra.w), a1[6]);  a1[7]  = fmaf(pj, bfh(ra.w), a1[7]);
        a1[8]  = fmaf(pj, bfl(rb.x), a1[8]);  a1[9]  = fmaf(pj, bfh(rb.x), a1[9]);
        a1[10] = fmaf(pj, bfl(rb.y), a1[10]); a1[11] = fmaf(pj, bfh(rb.y), a1[11]);
        a1[12] = fmaf(pj, bfl(rb.z), a1[12]); a1[13] = fmaf(pj, bfh(rb.z), a1[13]);
        a1[14] = fmaf(pj, bfl(rb.w), a1[14]); a1[15] = fmaf(pj, bfh(rb.w), a1[15]);
    }
#pragma unroll
    for (int c = 0; c < 16; ++c) a1[c] += __shfl_xor(a1[c], 1);
    {
        int cbase = (t & 1) * 8;
        float sce = F_SVE * rn;
        float* sop = so + ((size_t)b * CQKV + g * 32) * HLEN + i;
#pragma unroll
        for (int c8 = 0; c8 < 8; ++c8) {
            int c = cbase + c8;
            sop[(size_t)(2 * c + 1) * HLEN] = a1[c] * sce;
        }
    }

    __syncthreads();

    // ---- sv via MFMA: D(16i x 16c) = P-tile(16 x 32j) x V(32j x 16c) ----
    {
        int w = t >> 6, l = t & 63;
        int lr = l & 15, lh = l >> 4;
#pragma unroll
        for (int it = 0; it < 2; ++it) {
            int itile = w * 2 + it;
            float4v acc = {0.f, 0.f, 0.f, 0.f};
#pragma unroll
            for (int ks = 0; ks < 4; ++ks) {
                short8v af = *(const short8v*)&Pl[itile * 16 + lr][ks * 32 + lh * 8];
                short8v bf = *(const short8v*)&vB[lr][ks * 32 + lh * 8];
                acc = __builtin_amdgcn_mfma_f32_16x16x32_bf16(af, bf, acc, 0, 0, 0);
            }
            int oc = g * 32 + 2 * lr;                       // even slot = sv
            float* sop = so + ((size_t)b * CQKV + oc) * HLEN + itile * 16 + lh * 4;
            float4 outv;
            outv.x = acc[0] * F_SV; outv.y = acc[1] * F_SV;
            outv.z = acc[2] * F_SV; outv.w = acc[3] * F_SV;
            *(float4*)sop = outv;
        }
    }
}

// ---------------------------------------------------------------------------
// Final affine + pair-sum + transpose
// ---------------------------------------------------------------------------
__global__ __launch_bounds__(256) void k_out(const float* __restrict__ so,
                                             const float* __restrict__ scale,
                                             const float* __restrict__ shift,
                                             float* __restrict__ out) {
    int b = blockIdx.x, n = b >> 6, wi = b & 63;
    int t = threadIdx.x, h = t & 127, half = t >> 7;
    for (int oc = half * 64; oc < half * 64 + 64; ++oc) {
        float v0 = so[((size_t)b * CQKV + 2 * oc) * HLEN + h] * scale[2 * oc] + shift[2 * oc];
        float v1 = so[((size_t)b * CQKV + 2 * oc + 1) * HLEN + h] * scale[2 * oc + 1] + shift[2 * oc + 1];
        out[(((size_t)n * 128 + oc) * 64 + wi) * HLEN + h] = v0 + v1;
    }
}

extern "C" void kernel_launch(void* const* d_in, const int* in_sizes, int n_in,
                              void* d_out, int out_size, void* d_ws, size_t ws_size,
                              hipStream_t stream) {
    const float* x   = (const float*)d_in[0];
    const float* w   = (const float*)d_in[1];
    const float* g1  = (const float*)d_in[2];
    const float* b1  = (const float*)d_in[3];
    const float* g2  = (const float*)d_in[4];
    const float* b2  = (const float*)d_in[5];
    const float* gs  = (const float*)d_in[6];
    const float* bs  = (const float*)d_in[7];
    const float* go  = (const float*)d_in[8];
    const float* bo  = (const float*)d_in[9];
    const float* rel = (const float*)d_in[10];
    float* out = (float*)d_out;

    float*  qkv    = (float*)d_ws;                      // 16,777,216 f
    float*  so     = qkv + (size_t)16777216;            // 16,777,216 f
    double* accS   = (double*)(so + (size_t)16777216);  // 48 d
    float*  scaleA = (float*)(accS + 48);
    float*  shiftA = scaleA + 256;
    float*  scaleS = shiftA + 256;                      // 24
    float*  shiftS = scaleS + 24;
    float*  scaleF = shiftS + 24;                       // 256
    float*  shiftF = scaleF + 256;
    float*  Rq     = shiftF + 256;                      // 1024
    float*  Rk     = Rq + 1024;                         // 1024
    float*  TqT    = Rk + 1024;                         // 8192
    float*  TkT    = TqT + 8192;                        // 8192

    hipMemsetAsync(accS, 0, 48 * sizeof(double), stream);

    k_qkv<<<1024, 256, 0, stream>>>(x, w, qkv);
    k_tables<<<128, 128, 0, stream>>>(rel, Rq, Rk, TqT, TkT);
    k_chstats<0><<<256, 256, 0, stream>>>(qkv, g1, b1, g2, b2, scaleA, shiftA);
    k_gram<<<4096, 64, 0, stream>>>(qkv, scaleA, shiftA, Rq, Rk, TqT, TkT, accS);
    k_sfin<<<1, 32, 0, stream>>>(accS, gs, bs, scaleS, shiftS);
    k_attn<<<4096, 256, 0, stream>>>(qkv, scaleA, shiftA, rel, scaleS, shiftS, so);
    k_chstats<1><<<256, 256, 0, stream>>>(so, go, bo, nullptr, nullptr, scaleF, shiftF);
    k_out<<<512, 256, 0, stream>>>(so, scaleF, shiftF, out);
}

// Round 8
// 520.248 us; speedup vs baseline: 2.1263x; 1.0658x over previous
//
#include <hip/hip_runtime.h>
#include <hip/hip_fp16.h>
#include <math.h>

#define B_TOT 512
#define CQKV  256
#define CIN   128
#define HLEN  128

static constexpr float F_QR = 0.3f, F_KR = 0.3f, F_SV = 0.5f, F_SVE = 0.3f;
static constexpr float EPS = 1e-5f;

typedef __attribute__((ext_vector_type(8))) short short8v;
typedef __attribute__((ext_vector_type(8))) _Float16 half8v;
typedef __attribute__((ext_vector_type(4))) float float4v;

__device__ __forceinline__ unsigned short f2bf(float f) {
    unsigned u = __float_as_uint(f);
    unsigned r = u + 0x7fffu + ((u >> 16) & 1u);
    return (unsigned short)(r >> 16);
}
__device__ __forceinline__ unsigned short f2h(float f) {
    return __half_as_ushort(__float2half(f));
}

// ---------------------------------------------------------------------------
// Kernel 1 (MFMA): qkv[b][o][h] = sum_c w[o][c] * x[n][c][w][h]  (round-7)
// ---------------------------------------------------------------------------
__global__ __launch_bounds__(256, 3) void k_qkv(const float* __restrict__ x,
                                                const float* __restrict__ w,
                                                float* __restrict__ qkv) {
    __shared__ unsigned short As[64][136];
    __shared__ unsigned short Xs[256][64];
    int bid = blockIdx.x;
    int n   = bid >> 7;
    int sub = bid & 127;
    int mt  = sub >> 2;
    int ot  = sub & 3;
    int m0  = mt << 8;
    int o0  = ot << 6;
    int t   = threadIdx.x;

#pragma unroll
    for (int it = 0; it < 8; ++it) {
        int idx = it * 256 + t;
        int o = idx >> 5, c4 = (idx & 31) << 2;
        float4 wv = *(const float4*)(w + (size_t)(o0 + o) * CIN + c4);
        As[o][c4 + 0] = f2bf(wv.x);
        As[o][c4 + 1] = f2bf(wv.y);
        As[o][c4 + 2] = f2bf(wv.z);
        As[o][c4 + 3] = f2bf(wv.w);
    }

    const float* xn = x + (size_t)n * CIN * 8192 + m0;

    int wv_ = t >> 6, l = t & 63;
    int lr = l & 15, lh = l >> 4;
    int mw = wv_ << 6;

    float4v acc[4][4];
#pragma unroll
    for (int a = 0; a < 4; ++a)
#pragma unroll
        for (int b2 = 0; b2 < 4; ++b2) acc[a][b2] = (float4v){0.f, 0.f, 0.f, 0.f};

    for (int s = 0; s < 2; ++s) {
        int c0 = s << 6;
        __syncthreads();
#pragma unroll
        for (int it = 0; it < 16; ++it) {
            int c  = (it << 2) + (t >> 6);
            int m4 = (t & 63) << 2;
            float4 xv = *(const float4*)(xn + (size_t)(c0 + c) * 8192 + m4);
            float vals[4] = {xv.x, xv.y, xv.z, xv.w};
#pragma unroll
            for (int j = 0; j < 4; ++j) {
                int m = m4 + j;
                int cs = (((c >> 3) ^ ((m >> 2) & 7)) << 3) | (c & 7);
                Xs[m][cs] = f2bf(vals[j]);
            }
        }
        __syncthreads();
#pragma unroll
        for (int ks = 0; ks < 2; ++ks) {
            short8v af[4], bf[4];
#pragma unroll
            for (int a = 0; a < 4; ++a)
                af[a] = *(const short8v*)&As[a * 16 + lr][c0 + ks * 32 + lh * 8];
#pragma unroll
            for (int b2 = 0; b2 < 4; ++b2) {
                int m  = mw + b2 * 16 + lr;
                int cb = (ks * 4 + lh) ^ ((m >> 2) & 7);
                bf[b2] = *(const short8v*)&Xs[m][cb << 3];
            }
#pragma unroll
            for (int a = 0; a < 4; ++a)
#pragma unroll
                for (int b2 = 0; b2 < 4; ++b2)
                    acc[a][b2] = __builtin_amdgcn_mfma_f32_16x16x32_bf16(
                        af[a], bf[b2], acc[a][b2], 0, 0, 0);
        }
    }

#pragma unroll
    for (int a = 0; a < 4; ++a) {
#pragma unroll
        for (int b2 = 0; b2 < 4; ++b2) {
            int m  = m0 + mw + b2 * 16 + lr;
            int bb = n * 64 + (m >> 7);
            int h  = m & 127;
#pragma unroll
            for (int r = 0; r < 4; ++r) {
                int o = o0 + a * 16 + lh * 4 + r;
                qkv[((size_t)bb * CQKV + o) * HLEN + h] = acc[a][b2][r];
            }
        }
    }
}

// ---------------------------------------------------------------------------
// Kernel 2: per-channel stats -> fused affine (scale, shift)
// ---------------------------------------------------------------------------
template <int MODE>
__global__ __launch_bounds__(256) void k_chstats(const float* __restrict__ data,
                                                 const float* __restrict__ ga,
                                                 const float* __restrict__ ba,
                                                 const float* __restrict__ gb,
                                                 const float* __restrict__ bb,
                                                 float* __restrict__ scale,
                                                 float* __restrict__ shift) {
    int o = blockIdx.x;
    int t = threadIdx.x;
    double s = 0.0, ss = 0.0;
    for (int idx = t; idx < B_TOT * HLEN; idx += 256) {
        int b = idx >> 7, h = idx & 127;
        float v = data[((size_t)b * CQKV + o) * HLEN + h];
        s += v;
        ss += (double)v * v;
    }
    __shared__ double sh_s[256], sh_ss[256];
    sh_s[t] = s; sh_ss[t] = ss;
    __syncthreads();
    for (int off = 128; off > 0; off >>= 1) {
        if (t < off) { sh_s[t] += sh_s[t + off]; sh_ss[t] += sh_ss[t + off]; }
        __syncthreads();
    }
    if (t == 0) {
        double cnt  = (double)B_TOT * HLEN;
        double mean = sh_s[0] / cnt;
        double var  = sh_ss[0] / cnt - mean * mean;
        float sc, sf;
        if (MODE == 0) {
            float r1 = rsqrtf((float)var + EPS);
            float v2 = ga[o] * ga[o] * (float)var * r1 * r1;
            sc = ga[o] * gb[o] * r1 * rsqrtf(v2 + EPS);
            sf = bb[o] - (float)mean * sc;
        } else {
            sc = ga[o] * rsqrtf((float)var + EPS);
            sf = ba[o] - (float)mean * sc;
        }
        scale[o] = sc;
        shift[o] = sf;
    }
}

// ---------------------------------------------------------------------------
// Tables for analytic score stats.
// ---------------------------------------------------------------------------
__global__ __launch_bounds__(128) void k_tables(const float* __restrict__ rel,
                                                float* __restrict__ Rq, float* __restrict__ Rk,
                                                float* __restrict__ TqT, float* __restrict__ TkT) {
    int bid = blockIdx.x;      // 0..127
    int i = threadIdx.x;       // 0..127
    int p = bid & 63;
    int c = p >> 3, c2 = p & 7;
    const float* ra = (bid < 64) ? (rel + c * 255)  : (rel + (8 + c) * 255);
    const float* rb = (bid < 64) ? (rel + c2 * 255) : (rel + (8 + c2) * 255);
    float tacc = 0.f;
    for (int kk = 0; kk < 128; ++kk) tacc = fmaf(ra[i + kk], rb[i + kk], tacc);
    if (bid < 64) TqT[i * 64 + p] = tacc; else TkT[i * 64 + p] = tacc;
    if (c2 == 0) {
        float racc = 0.f;
        for (int kk = 0; kk < 128; ++kk) racc += ra[i + kk];
        if (bid < 64) Rq[c * 128 + i] = racc; else Rk[c * 128 + i] = racc;
    }
}

// ---------------------------------------------------------------------------
// Analytic score stats per (b,g).
// ---------------------------------------------------------------------------
__global__ __launch_bounds__(64) void k_gram(const float* __restrict__ qkv,
                                             const float* __restrict__ scaleA,
                                             const float* __restrict__ shiftA,
                                             const float* __restrict__ Rq,
                                             const float* __restrict__ Rk,
                                             const float* __restrict__ TqT,
                                             const float* __restrict__ TkT,
                                             double* __restrict__ accS) {
    __shared__ float qs[8][132], ks[8][132];
    int blk = blockIdx.x, b = blk >> 3, g = blk & 7;
    int t = threadIdx.x;
    for (int idx = t; idx < 2048; idx += 64) {
        int cc = idx >> 7, h = idx & 127, o = g * 32 + cc;
        float v = qkv[((size_t)b * CQKV + o) * HLEN + h] * scaleA[o] + shiftA[o];
        if (cc < 8) qs[cc][h] = v; else ks[cc - 8][h] = v;
    }
    __syncthreads();
    int c = t >> 3, c2 = t & 7;
    float gq = 0, gk = 0, tq = 0, tk = 0;
    for (int i = 0; i < 128; ++i) {
        float a = qs[c][i] * qs[c2][i];
        float e = ks[c][i] * ks[c2][i];
        gq += a; gk += e;
        tq = fmaf(a, TqT[i * 64 + t], tq);
        tk = fmaf(e, TkT[i * 64 + t], tk);
    }
    float ssqk = gq * gk;
    float sqr = 0, skr = 0;
    float sq8[8], sk8[8];
#pragma unroll
    for (int c3 = 0; c3 < 8; ++c3) {
        float q0 = qs[c3][t], q1 = qs[c3][t + 64];
        float k0 = ks[c3][t], k1 = ks[c3][t + 64];
        sq8[c3] = q0 + q1; sk8[c3] = k0 + k1;
        sqr = fmaf(q0, Rq[c3 * 128 + t], sqr);
        sqr = fmaf(q1, Rq[c3 * 128 + t + 64], sqr);
        skr = fmaf(k0, Rk[c3 * 128 + t], skr);
        skr = fmaf(k1, Rk[c3 * 128 + t + 64], skr);
    }
#pragma unroll
    for (int off = 1; off < 64; off <<= 1) {
        ssqk += __shfl_xor(ssqk, off);
        tq   += __shfl_xor(tq, off);
        tk   += __shfl_xor(tk, off);
        sqr  += __shfl_xor(sqr, off);
        skr  += __shfl_xor(skr, off);
#pragma unroll
        for (int c3 = 0; c3 < 8; ++c3) {
            sq8[c3] += __shfl_xor(sq8[c3], off);
            sk8[c3] += __shfl_xor(sk8[c3], off);
        }
    }
    if (t == 0) {
        float sqk = 0;
#pragma unroll
        for (int c3 = 0; c3 < 8; ++c3) sqk += sq8[c3] * sk8[c3];
        atomicAdd(&accS[g * 2 + 0], (double)sqk);
        atomicAdd(&accS[g * 2 + 1], (double)ssqk);
        atomicAdd(&accS[(8 + g) * 2 + 0], (double)(F_QR * sqr));
        atomicAdd(&accS[(8 + g) * 2 + 1], (double)(F_QR * F_QR * tq));
        atomicAdd(&accS[(16 + g) * 2 + 0], (double)(F_KR * skr));
        atomicAdd(&accS[(16 + g) * 2 + 1], (double)(F_KR * F_KR * tk));
    }
}

__global__ void k_sfin(const double* __restrict__ accS,
                       const float* __restrict__ gs, const float* __restrict__ bs,
                       float* __restrict__ scaleS, float* __restrict__ shiftS) {
    int c = threadIdx.x;
    if (c < 24) {
        double cnt  = 512.0 * 128.0 * 128.0;
        double mean = accS[c * 2] / cnt;
        double var  = accS[c * 2 + 1] / cnt - mean * mean;
        float sc = gs[c] * rsqrtf((float)var + EPS);
        scaleS[c] = sc;
        shiftS[c] = bs[c] - (float)mean * sc;
    }
}

// ---------------------------------------------------------------------------
// Attention (f16 packed-math version):
//  - q/k/rel/P/V all f16 in LDS; dots via __hfma2 (v_pk_fma_f16): 2 MAC/inst,
//    zero unpack cost (was 16 unpack VALU ops per jj in score AND sve).
//  - scores combined + softmax in f32; sve accumulated in half2 (err ~5e-3 rel).
//  - sv via mfma_f32_16x16x32_f16 (same verified fragment layout).
//  - LDS 59.6 KB -> 2 blocks/CU (unchanged).
// ---------------------------------------------------------------------------
__global__ __launch_bounds__(256, 4) void k_attn(const float* __restrict__ qkv,
                                                 const float* __restrict__ scaleA,
                                                 const float* __restrict__ shiftA,
                                                 const float* __restrict__ rel,
                                                 const float* __restrict__ scaleS,
                                                 const float* __restrict__ shiftS,
                                                 float* __restrict__ so) {
    __shared__ unsigned short qT[128][8];    // f16, row=i
    __shared__ unsigned short kF[128][8];    // f16, row=j
    __shared__ unsigned short vB[16][136];   // f16, row=c (sv B-frags)
    __shared__ unsigned short rqT[255][8];   // f16
    __shared__ unsigned short rkT[255][8];
    __shared__ unsigned short rvA[255][8];
    __shared__ unsigned short rvB[255][8];
    __shared__ unsigned short Pl[128][136];  // f16 P*rn
    int blk = blockIdx.x, b = blk >> 3, g = blk & 7;
    int t = threadIdx.x;
    for (int idx = t; idx < 32 * 128; idx += 256) {
        int cc = idx >> 7, h = idx & 127, o = g * 32 + cc;
        float v = qkv[((size_t)b * CQKV + o) * HLEN + h] * scaleA[o] + shiftA[o];
        if (cc < 8)       qT[h][cc] = f2h(v);
        else if (cc < 16) kF[h][cc - 8] = f2h(v);
        else              vB[cc - 16][h] = f2h(v);
    }
    for (int idx = t; idx < 32 * 255; idx += 256) {
        int r = idx / 255, d = idx - r * 255;
        unsigned short us = f2h(rel[r * 255 + d]);
        if (r < 8)       rqT[d][r] = us;
        else if (r < 16) rkT[d][r - 8] = us;
        else if (r < 24) rvA[d][r - 16] = us;
        else             rvB[d][r - 24] = us;
    }
    __syncthreads();

    float cA = scaleS[g], cB = F_QR * scaleS[8 + g], cC = F_KR * scaleS[16 + g];
    float shsum = shiftS[g] + shiftS[8 + g] + shiftS[16 + g];

    int i = t >> 1, j0 = (t & 1) << 6;
    __half2 q2[4];
    {
        uint4 qv = *(const uint4*)&qT[i][0];
        q2[0] = *(__half2*)&qv.x; q2[1] = *(__half2*)&qv.y;
        q2[2] = *(__half2*)&qv.z; q2[3] = *(__half2*)&qv.w;
    }

    float p[64];
    float rowmax = -1e30f;
#pragma unroll
    for (int jj = 0; jj < 64; ++jj) {
        int j = j0 + jj;
        uint4 kv = *(const uint4*)&kF[j][0];
        uint4 rq = *(const uint4*)&rqT[i - j + 127][0];
        uint4 rk = *(const uint4*)&rkT[j - i + 127][0];
        __half2* k2  = (__half2*)&kv;
        __half2* rq2 = (__half2*)&rq;
        __half2* rk2 = (__half2*)&rk;
        __half2 hqk = __hfma2(q2[0], k2[0], __hfma2(q2[1], k2[1],
                      __hfma2(q2[2], k2[2], __hmul2(q2[3], k2[3]))));
        __half2 hqr = __hfma2(q2[0], rq2[0], __hfma2(q2[1], rq2[1],
                      __hfma2(q2[2], rq2[2], __hmul2(q2[3], rq2[3]))));
        __half2 hkr = __hfma2(k2[0], rk2[0], __hfma2(k2[1], rk2[1],
                      __hfma2(k2[2], rk2[2], __hmul2(k2[3], rk2[3]))));
        float qk = __low2float(hqk) + __high2float(hqk);
        float qr = __low2float(hqr) + __high2float(hqr);
        float kr = __low2float(hkr) + __high2float(hkr);
        float s = fmaf(qk, cA, fmaf(qr, cB, fmaf(kr, cC, shsum)));
        p[jj] = s;
        rowmax = fmaxf(rowmax, s);
    }
    rowmax = fmaxf(rowmax, __shfl_xor(rowmax, 1));
    float rsum = 0.f;
#pragma unroll
    for (int jj = 0; jj < 64; ++jj) {
        float e = __expf(p[jj] - rowmax);
        p[jj] = e;
        rsum += e;
    }
    rsum += __shfl_xor(rsum, 1);
    float rn = 1.f / rsum;

    // ---- write P*rn as f16 to LDS ----
#pragma unroll
    for (int k = 0; k < 32; ++k) {
        __half2 h2 = __floats2half2_rn(p[2 * k] * rn, p[2 * k + 1] * rn);
        *(unsigned*)&Pl[i][j0 + 2 * k] = *(unsigned*)&h2;
    }

    // ---- sve = P (*) v_emb: packed f16 MACs, half2 accumulators ----
    __half2 acc2[8];
#pragma unroll
    for (int m = 0; m < 8; ++m) acc2[m] = __floats2half2_rn(0.f, 0.f);
#pragma unroll
    for (int jj = 0; jj < 64; ++jj) {
        int j = j0 + jj;
        int d = i - j + 127;
        __half2 p2 = __float2half2_rn(p[jj]);
        uint4 ra = *(const uint4*)&rvA[d][0];
        uint4 rb = *(const uint4*)&rvB[d][0];
        __half2* ra2 = (__half2*)&ra;
        __half2* rb2 = (__half2*)&rb;
        acc2[0] = __hfma2(p2, ra2[0], acc2[0]);
        acc2[1] = __hfma2(p2, ra2[1], acc2[1]);
        acc2[2] = __hfma2(p2, ra2[2], acc2[2]);
        acc2[3] = __hfma2(p2, ra2[3], acc2[3]);
        acc2[4] = __hfma2(p2, rb2[0], acc2[4]);
        acc2[5] = __hfma2(p2, rb2[1], acc2[5]);
        acc2[6] = __hfma2(p2, rb2[2], acc2[6]);
        acc2[7] = __hfma2(p2, rb2[3], acc2[7]);
    }
    float a1[16];
#pragma unroll
    for (int m = 0; m < 8; ++m) {
        a1[2 * m]     = __low2float(acc2[m]);
        a1[2 * m + 1] = __high2float(acc2[m]);
    }
#pragma unroll
    for (int c = 0; c < 16; ++c) a1[c] += __shfl_xor(a1[c], 1);
    {
        int cbase = (t & 1) * 8;
        float sce = F_SVE * rn;
        float* sop = so + ((size_t)b * CQKV + g * 32) * HLEN + i;
#pragma unroll
        for (int c8 = 0; c8 < 8; ++c8) {
            int c = cbase + c8;
            sop[(size_t)(2 * c + 1) * HLEN] = a1[c] * sce;
        }
    }

    __syncthreads();

    // ---- sv via MFMA (f16): D(16i x 16c) = P-tile(16 x 32j) x V(32j x 16c) ----
    {
        int w = t >> 6, l = t & 63;
        int lr = l & 15, lh = l >> 4;
#pragma unroll
        for (int it = 0; it < 2; ++it) {
            int itile = w * 2 + it;
            float4v acc = {0.f, 0.f, 0.f, 0.f};
#pragma unroll
            for (int ks = 0; ks < 4; ++ks) {
                half8v af = *(const half8v*)&Pl[itile * 16 + lr][ks * 32 + lh * 8];
                half8v bf = *(const half8v*)&vB[lr][ks * 32 + lh * 8];
                acc = __builtin_amdgcn_mfma_f32_16x16x32_f16(af, bf, acc, 0, 0, 0);
            }
            int oc = g * 32 + 2 * lr;                       // even slot = sv
            float* sop = so + ((size_t)b * CQKV + oc) * HLEN + itile * 16 + lh * 4;
            float4 outv;
            outv.x = acc[0] * F_SV; outv.y = acc[1] * F_SV;
            outv.z = acc[2] * F_SV; outv.w = acc[3] * F_SV;
            *(float4*)sop = outv;
        }
    }
}

// ---------------------------------------------------------------------------
// Final affine + pair-sum + transpose
// ---------------------------------------------------------------------------
__global__ __launch_bounds__(256) void k_out(const float* __restrict__ so,
                                             const float* __restrict__ scale,
                                             const float* __restrict__ shift,
                                             float* __restrict__ out) {
    int b = blockIdx.x, n = b >> 6, wi = b & 63;
    int t = threadIdx.x, h = t & 127, half = t >> 7;
    for (int oc = half * 64; oc < half * 64 + 64; ++oc) {
        float v0 = so[((size_t)b * CQKV + 2 * oc) * HLEN + h] * scale[2 * oc] + shift[2 * oc];
        float v1 = so[((size_t)b * CQKV + 2 * oc + 1) * HLEN + h] * scale[2 * oc + 1] + shift[2 * oc + 1];
        out[(((size_t)n * 128 + oc) * 64 + wi) * HLEN + h] = v0 + v1;
    }
}

extern "C" void kernel_launch(void* const* d_in, const int* in_sizes, int n_in,
                              void* d_out, int out_size, void* d_ws, size_t ws_size,
                              hipStream_t stream) {
    const float* x   = (const float*)d_in[0];
    const float* w   = (const float*)d_in[1];
    const float* g1  = (const float*)d_in[2];
    const float* b1  = (const float*)d_in[3];
    const float* g2  = (const float*)d_in[4];
    const float* b2  = (const float*)d_in[5];
    const float* gs  = (const float*)d_in[6];
    const float* bs  = (const float*)d_in[7];
    const float* go  = (const float*)d_in[8];
    const float* bo  = (const float*)d_in[9];
    const float* rel = (const float*)d_in[10];
    float* out = (float*)d_out;

    float*  qkv    = (float*)d_ws;                      // 16,777,216 f
    float*  so     = qkv + (size_t)16777216;            // 16,777,216 f
    double* accS   = (double*)(so + (size_t)16777216);  // 48 d
    float*  scaleA = (float*)(accS + 48);
    float*  shiftA = scaleA + 256;
    float*  scaleS = shiftA + 256;                      // 24
    float*  shiftS = scaleS + 24;
    float*  scaleF = shiftS + 24;                       // 256
    float*  shiftF = scaleF + 256;
    float*  Rq     = shiftF + 256;                      // 1024
    float*  Rk     = Rq + 1024;                         // 1024
    float*  TqT    = Rk + 1024;                         // 8192
    float*  TkT    = TqT + 8192;                        // 8192

    hipMemsetAsync(accS, 0, 48 * sizeof(double), stream);

    k_qkv<<<1024, 256, 0, stream>>>(x, w, qkv);
    k_tables<<<128, 128, 0, stream>>>(rel, Rq, Rk, TqT, TkT);
    k_chstats<0><<<256, 256, 0, stream>>>(qkv, g1, b1, g2, b2, scaleA, shiftA);
    k_gram<<<4096, 64, 0, stream>>>(qkv, scaleA, shiftA, Rq, Rk, TqT, TkT, accS);
    k_sfin<<<1, 32, 0, stream>>>(accS, gs, bs, scaleS, shiftS);
    k_attn<<<4096, 256, 0, stream>>>(qkv, scaleA, shiftA, rel, scaleS, shiftS, so);
    k_chstats<1><<<256, 256, 0, stream>>>(so, go, bo, nullptr, nullptr, scaleF, shiftF);
    k_out<<<512, 256, 0, stream>>>(so, scaleF, shiftF, out);
}